// Round 3
// baseline (1752.746 us; speedup 1.0000x reference)
//
#include <hip/hip_runtime.h>
#include <hip/hip_bf16.h>
#include <math.h>

#define B_ 8
#define S_ 192
#define D_ 512
#define L_ 8
#define SQ 1536   // S_*L_
#define H_ 2048
#define NROW (B_*SQ)   // 12288
#define SCALE_QK 0.04419417382415922f  // 1/sqrt(512)

// ---- build x rows [b_base*SQ ..]: (B,s,d,L) fp32 -> (rows, d) fp32, diagnostic clamp ----
__global__ __launch_bounds__(256) void k_build_x(const float* __restrict__ lags,
                                                 float* __restrict__ x, int b_base) {
  int idx = blockIdx.x * 256 + threadIdx.x;       // over nrows*D_
  int k = idx & (D_ - 1);
  int r = idx >> 9;                               // local row id
  int b = b_base + r / SQ;
  int t = r - (r / SQ) * SQ;
  int si = t >> 3, l = t & 7;
  size_t src = (((size_t)(b * S_ + si) * D_ + k) << 3) + l;
  float v = lags[src];
  // diagnostic clamp: no-op for valid N(0,1) fp32 input
  if (!(v == v) || fabsf(v) > 1e6f) v = 0.0f;
  x[idx] = v;
}

// ---------------- scores = scale * X X^T ----------------
#define TS 64
#define KT 16
__global__ __launch_bounds__(256) void k_scores(const float* __restrict__ x,
                                                float* __restrict__ sc,
                                                int b_base, int x_full) {
  int z = blockIdx.z;
  const float* A = x + (size_t)(x_full ? (b_base + z) : 0) * SQ * D_;
  float* C = sc + (size_t)z * SQ * SQ;
  __shared__ float As[TS][KT + 1];
  __shared__ float Bs[TS][KT + 1];
  int tx = threadIdx.x & 15, ty = threadIdx.x >> 4;
  int j0 = blockIdx.x * TS, i0 = blockIdx.y * TS;
  float acc[4][4] = {};
  int lk = threadIdx.x & 15, lr = threadIdx.x >> 4;
  for (int k0 = 0; k0 < D_; k0 += KT) {
    #pragma unroll
    for (int it = 0; it < 4; ++it) {
      As[lr + 16 * it][lk] = A[(size_t)(i0 + lr + 16 * it) * D_ + k0 + lk];
      Bs[lr + 16 * it][lk] = A[(size_t)(j0 + lr + 16 * it) * D_ + k0 + lk];
    }
    __syncthreads();
    #pragma unroll
    for (int kk = 0; kk < KT; ++kk) {
      float a[4], bb[4];
      #pragma unroll
      for (int r = 0; r < 4; ++r) a[r] = As[ty * 4 + r][kk];
      #pragma unroll
      for (int c = 0; c < 4; ++c) bb[c] = Bs[tx * 4 + c][kk];
      #pragma unroll
      for (int r = 0; r < 4; ++r)
        #pragma unroll
        for (int c = 0; c < 4; ++c) acc[r][c] = fmaf(a[r], bb[c], acc[r][c]);
    }
    __syncthreads();
  }
  #pragma unroll
  for (int r = 0; r < 4; ++r) {
    float4 v = make_float4(acc[r][0]*SCALE_QK, acc[r][1]*SCALE_QK,
                           acc[r][2]*SCALE_QK, acc[r][3]*SCALE_QK);
    *reinterpret_cast<float4*>(&C[(size_t)(i0 + ty*4 + r) * SQ + j0 + tx*4]) = v;
  }
}

// ---------------- softmax rows in place ----------------
__global__ __launch_bounds__(256) void k_softmax(float* __restrict__ sc) {
  float* row = sc + (size_t)blockIdx.z * SQ * SQ + (size_t)blockIdx.x * SQ;
  int tid = threadIdx.x;
  __shared__ float red[8];
  float m = -1e30f;
  for (int j = tid; j < SQ; j += 256) m = fmaxf(m, row[j]);
  #pragma unroll
  for (int o = 32; o > 0; o >>= 1) m = fmaxf(m, __shfl_down(m, o));
  if ((tid & 63) == 0) red[tid >> 6] = m;
  __syncthreads();
  m = fmaxf(fmaxf(red[0], red[1]), fmaxf(red[2], red[3]));
  __syncthreads();
  float ssum = 0.f;
  for (int j = tid; j < SQ; j += 256) { float e = expf(row[j] - m); row[j] = e; ssum += e; }
  #pragma unroll
  for (int o = 32; o > 0; o >>= 1) ssum += __shfl_down(ssum, o);
  if ((tid & 63) == 0) red[4 + (tid >> 6)] = ssum;
  __syncthreads();
  float inv = 1.0f / (red[4] + red[5] + red[6] + red[7]);
  for (int j = tid; j < SQ; j += 256) row[j] *= inv;
}

// ---------------- attn_out = P @ X ----------------
__global__ __launch_bounds__(256) void k_attn(const float* __restrict__ x,
                                              const float* __restrict__ sc,
                                              float* __restrict__ attn,
                                              int b_base, int x_full) {
  int z = blockIdx.z;
  size_t boff = (size_t)(x_full ? (b_base + z) : 0) * SQ * D_;
  const float* X = x + boff;
  const float* P = sc + (size_t)z * SQ * SQ;
  float* O = attn + (x_full ? boff : (size_t)0);
  __shared__ float Ps[TS][KT + 1];
  __shared__ float Xs[KT][TS];
  int tx = threadIdx.x & 15, ty = threadIdx.x >> 4;
  int j0 = blockIdx.x * TS, i0 = blockIdx.y * TS;
  float acc[4][4] = {};
  int lk = threadIdx.x & 15, lr = threadIdx.x >> 4;
  int lc = threadIdx.x & 63, lrow = threadIdx.x >> 6;
  for (int k0 = 0; k0 < SQ; k0 += KT) {
    #pragma unroll
    for (int it = 0; it < 4; ++it)
      Ps[lr + 16 * it][lk] = P[(size_t)(i0 + lr + 16 * it) * SQ + k0 + lk];
    #pragma unroll
    for (int it = 0; it < 4; ++it)
      Xs[lrow + 4 * it][lc] = X[(size_t)(k0 + lrow + 4 * it) * D_ + j0 + lc];
    __syncthreads();
    #pragma unroll
    for (int kk = 0; kk < KT; ++kk) {
      float a[4], bb[4];
      #pragma unroll
      for (int r = 0; r < 4; ++r) a[r] = Ps[ty * 4 + r][kk];
      #pragma unroll
      for (int c = 0; c < 4; ++c) bb[c] = Xs[kk][tx * 4 + c];
      #pragma unroll
      for (int r = 0; r < 4; ++r)
        #pragma unroll
        for (int c = 0; c < 4; ++c) acc[r][c] = fmaf(a[r], bb[c], acc[r][c]);
    }
    __syncthreads();
  }
  #pragma unroll
  for (int r = 0; r < 4; ++r) {
    float4 v = make_float4(acc[r][0], acc[r][1], acc[r][2], acc[r][3]);
    *reinterpret_cast<float4*>(&O[(size_t)(i0 + ty*4 + r) * D_ + j0 + tx*4]) = v;
  }
}

// ---------------- LN1: q = LN(x + attn) ----------------
__global__ __launch_bounds__(256) void k_ln1(const float* __restrict__ x,
                                             const float* __restrict__ attn,
                                             const float* __restrict__ g,
                                             const float* __restrict__ be,
                                             float* __restrict__ qout) {
  size_t base = (size_t)blockIdx.x * D_;
  int tid = threadIdx.x;
  __shared__ float rl[8];
  float v0 = x[base + tid] + attn[base + tid];
  float v1 = x[base + tid + 256] + attn[base + tid + 256];
  float s = v0 + v1, sq = v0 * v0 + v1 * v1;
  #pragma unroll
  for (int o = 32; o > 0; o >>= 1) { s += __shfl_down(s, o); sq += __shfl_down(sq, o); }
  int lane = tid & 63, wid = tid >> 6;
  if (lane == 0) { rl[wid] = s; rl[4 + wid] = sq; }
  __syncthreads();
  s = rl[0] + rl[1] + rl[2] + rl[3];
  sq = rl[4] + rl[5] + rl[6] + rl[7];
  float mean = s * (1.0f / 512.0f);
  float var = sq * (1.0f / 512.0f) - mean * mean;
  float rstd = rsqrtf(var + 1e-5f);
  qout[base + tid]       = (v0 - mean) * rstd * g[tid] + be[tid];
  qout[base + tid + 256] = (v1 - mean) * rstd * g[tid + 256] + be[tid + 256];
}

// ---------------- FFN + residual + LN3 + output transpose (8 rows/block) ----------------
__global__ __launch_bounds__(256, 2) void k_ffn(
    const float* __restrict__ q,
    const float* __restrict__ W1, const float* __restrict__ b1,
    const float* __restrict__ W2, const float* __restrict__ b2,
    const float* __restrict__ g3, const float* __restrict__ be3,
    float* __restrict__ out, int row_base)
{
  __shared__ float qs[8][D_];    // 16 KB
  __shared__ float mid[8][H_];   // 64 KB  (reused as ys later)
  const int tid = threadIdx.x;
  const int row0 = blockIdx.x * 8;   // local row into q buffer

  for (int idx = tid; idx < 8 * D_; idx += 256)
    qs[idx >> 9][idx & (D_ - 1)] = q[(size_t)row0 * D_ + idx];
  __syncthreads();

  // ---- phase 1: mid = gelu(q @ W1 + b1); thread owns j = tid*8 .. tid*8+7
  float acc[8][8];  // [jj][r]
  {
    float4 bA = *reinterpret_cast<const float4*>(b1 + (tid << 3));
    float4 bB = *reinterpret_cast<const float4*>(b1 + (tid << 3) + 4);
    float bv[8] = {bA.x, bA.y, bA.z, bA.w, bB.x, bB.y, bB.z, bB.w};
    #pragma unroll
    for (int jj = 0; jj < 8; ++jj)
      #pragma unroll
      for (int r = 0; r < 8; ++r) acc[jj][r] = bv[jj];
  }
  for (int k4 = 0; k4 < D_ / 4; ++k4) {
    float4 qv[8];
    #pragma unroll
    for (int r = 0; r < 8; ++r)
      qv[r] = *reinterpret_cast<const float4*>(&qs[r][k4 << 2]);
    #pragma unroll
    for (int kk = 0; kk < 4; ++kk) {
      const int k = (k4 << 2) + kk;
      float4 wA = *reinterpret_cast<const float4*>(W1 + (size_t)k * H_ + (tid << 3));
      float4 wB = *reinterpret_cast<const float4*>(W1 + (size_t)k * H_ + (tid << 3) + 4);
      float w[8] = {wA.x, wA.y, wA.z, wA.w, wB.x, wB.y, wB.z, wB.w};
      #pragma unroll
      for (int r = 0; r < 8; ++r) {
        float qk = (kk == 0) ? qv[r].x : (kk == 1) ? qv[r].y : (kk == 2) ? qv[r].z : qv[r].w;
        #pragma unroll
        for (int jj = 0; jj < 8; ++jj) acc[jj][r] = fmaf(qk, w[jj], acc[jj][r]);
      }
    }
  }
  #pragma unroll
  for (int jj = 0; jj < 8; ++jj)
    #pragma unroll
    for (int r = 0; r < 8; ++r) {
      float v = acc[jj][r];
      mid[r][(tid << 3) + jj] = 0.5f * v * (1.0f + erff(v * 0.70710678118654752f));
    }
  __syncthreads();

  // ---- phase 2: ff = mid @ W2 + b2; thread owns i = tid*2, tid*2+1
  float acc2[8][2];
  {
    float b20 = b2[tid << 1], b21 = b2[(tid << 1) + 1];
    #pragma unroll
    for (int r = 0; r < 8; ++r) { acc2[r][0] = b20; acc2[r][1] = b21; }
  }
  for (int j4 = 0; j4 < H_ / 4; ++j4) {
    float4 mv[8];
    #pragma unroll
    for (int r = 0; r < 8; ++r)
      mv[r] = *reinterpret_cast<const float4*>(&mid[r][j4 << 2]);
    #pragma unroll
    for (int kk = 0; kk < 4; ++kk) {
      const int j = (j4 << 2) + kk;
      float2 wv = *reinterpret_cast<const float2*>(W2 + (size_t)j * D_ + (tid << 1));
      #pragma unroll
      for (int r = 0; r < 8; ++r) {
        float m = (kk == 0) ? mv[r].x : (kk == 1) ? mv[r].y : (kk == 2) ? mv[r].z : mv[r].w;
        acc2[r][0] = fmaf(m, wv.x, acc2[r][0]);
        acc2[r][1] = fmaf(m, wv.y, acc2[r][1]);
      }
    }
  }
  __syncthreads();  // all mid reads done before overwrite

  // ---- y = q + ff  (reuse mid LDS as ys[8][512])
  float* ys = &mid[0][0];
  #pragma unroll
  for (int r = 0; r < 8; ++r) {
    ys[r * D_ + (tid << 1)]     = qs[r][(tid << 1)]     + acc2[r][0];
    ys[r * D_ + (tid << 1) + 1] = qs[r][(tid << 1) + 1] + acc2[r][1];
  }
  __syncthreads();

  float g3a = g3[tid],  g3b = g3[tid + 256];
  float be3a = be3[tid], be3b = be3[tid + 256];
  float* rl = &qs[0][0];  // qs no longer needed: reuse for reductions

  for (int r = 0; r < 8; ++r) {
    float v0 = ys[r * D_ + tid], v1 = ys[r * D_ + tid + 256];
    float s = v0 + v1, sq = v0 * v0 + v1 * v1;
    #pragma unroll
    for (int o = 32; o > 0; o >>= 1) { s += __shfl_down(s, o); sq += __shfl_down(sq, o); }
    int lane = tid & 63, wid = tid >> 6;
    if (lane == 0) { rl[wid] = s; rl[4 + wid] = sq; }
    __syncthreads();
    s = rl[0] + rl[1] + rl[2] + rl[3];
    sq = rl[4] + rl[5] + rl[6] + rl[7];
    __syncthreads();
    float mean = s * (1.0f / 512.0f);
    float var = sq * (1.0f / 512.0f) - mean * mean;
    float rstd = rsqrtf(var + 1e-5f);
    int t = row_base + row0 + r;              // global row
    int b = t / SQ, tt = t - b * SQ;
    int si = tt >> 3, l = tt & 7;
    size_t ob = (((size_t)(b * S_ + si) * D_) << 3) + l;   // + k*8 per element
    out[ob + ((size_t)tid << 3)]         = (v0 - mean) * rstd * g3a + be3a;
    out[ob + ((size_t)(tid + 256) << 3)] = (v1 - mean) * rstd * g3b + be3b;
  }
}

extern "C" void kernel_launch(void* const* d_in, const int* in_sizes, int n_in,
                              void* d_out, int out_size, void* d_ws, size_t ws_size,
                              hipStream_t stream) {
  const float* lags   = (const float*)d_in[0];
  const float* gamma1 = (const float*)d_in[1];
  const float* beta1  = (const float*)d_in[2];
  const float* W1     = (const float*)d_in[3];
  const float* b1     = (const float*)d_in[4];
  const float* W2     = (const float*)d_in[5];
  const float* b2     = (const float*)d_in[6];
  const float* g3     = (const float*)d_in[7];
  const float* be3    = (const float*)d_in[8];
  float* out = (float*)d_out;

  float* ws = (float*)d_ws;
  const size_t NX  = (size_t)B_ * SQ * D_;   // 6,291,456
  const size_t NXB = (size_t)SQ * D_;        //   786,432 (one batch)
  const size_t NS  = (size_t)SQ * SQ;        // 2,359,296

  const size_t need_full = (3 * NX + 8 * NS) * sizeof(float);  // ~151 MB

  if (ws_size >= need_full) {
    // ---- fast path: everything resident, batched grids ----
    float* x    = ws;
    float* attn = x + NX;
    float* q    = attn + NX;
    float* sc   = q + NX;
    k_build_x<<<dim3((unsigned)(NX / 256)), 256, 0, stream>>>(lags, x, 0);
    k_scores<<<dim3(SQ / TS, SQ / TS, 8), 256, 0, stream>>>(x, sc, 0, 1);
    k_softmax<<<dim3(SQ, 1, 8), 256, 0, stream>>>(sc);
    k_attn<<<dim3(D_ / TS, SQ / TS, 8), 256, 0, stream>>>(x, sc, attn, 0, 1);
    k_ln1<<<dim3(NROW), 256, 0, stream>>>(x, attn, gamma1, beta1, q);
    k_ffn<<<dim3(NROW / 8), 256, 0, stream>>>(q, W1, b1, W2, b2, g3, be3, out, 0);
  } else {
    // ---- minimal-footprint path: ~18.9 MB, per-batch serial ----
    float* xb   = ws;            // NXB floats
    float* sc   = xb + NXB;      // NS floats
    float* atb  = sc + NS;       // NXB floats
    float* qb   = atb + NXB;     // NXB floats
    for (int b = 0; b < B_; ++b) {
      k_build_x<<<dim3((unsigned)(NXB / 256)), 256, 0, stream>>>(lags, xb, b);
      k_scores<<<dim3(SQ / TS, SQ / TS, 1), 256, 0, stream>>>(xb, sc, b, 0);
      k_softmax<<<dim3(SQ, 1, 1), 256, 0, stream>>>(sc);
      k_attn<<<dim3(D_ / TS, SQ / TS, 1), 256, 0, stream>>>(xb, sc, atb, b, 0);
      k_ln1<<<dim3(SQ), 256, 0, stream>>>(xb, atb, gamma1, beta1, qb);
      k_ffn<<<dim3(SQ / 8), 256, 0, stream>>>(qb, W1, b1, W2, b2, g3, be3, out, b * SQ);
    }
  }
}

// Round 4
// 1012.654 us; speedup vs baseline: 1.7308x; 1.7308x over previous
//
#include <hip/hip_runtime.h>
#include <hip/hip_bf16.h>
#include <math.h>

#define B_ 8
#define S_ 192
#define D_ 512
#define L_ 8
#define SQ 1536   // S_*L_
#define H_ 2048
#define NROW (B_*SQ)   // 12288
#define SCALE_QK 0.04419417382415922f  // 1/sqrt(512)

typedef unsigned short ushort_t;
typedef __attribute__((ext_vector_type(8))) short bf16x8;
typedef __attribute__((ext_vector_type(4))) float f32x4;

__device__ __forceinline__ float bfu2f(ushort_t u) { return __uint_as_float((unsigned)u << 16); }
__device__ __forceinline__ ushort_t f2bfu(float f) {
  __hip_bfloat16 h = __float2bfloat16(f);
  return *reinterpret_cast<ushort_t*>(&h);
}

// ---- build x rows: (B,s,d,L) fp32 -> (rows, d) fp32 ----
__global__ __launch_bounds__(256) void k_build_x(const float* __restrict__ lags,
                                                 float* __restrict__ x, int b_base) {
  int idx = blockIdx.x * 256 + threadIdx.x;
  int k = idx & (D_ - 1);
  int r = idx >> 9;
  int b = b_base + r / SQ;
  int t = r - (r / SQ) * SQ;
  int si = t >> 3, l = t & 7;
  size_t src = (((size_t)(b * S_ + si) * D_ + k) << 3) + l;
  x[idx] = lags[src];
}

// ---------------- scores = scale * X X^T (fp32 path) ----------------
#define TS 64
#define KT 16
__global__ __launch_bounds__(256) void k_scores(const float* __restrict__ x,
                                                float* __restrict__ sc,
                                                int b_base, int x_full) {
  int z = blockIdx.z;
  const float* A = x + (size_t)(x_full ? (b_base + z) : 0) * SQ * D_;
  float* C = sc + (size_t)z * SQ * SQ;
  __shared__ float As[TS][KT + 1];
  __shared__ float Bs[TS][KT + 1];
  int tx = threadIdx.x & 15, ty = threadIdx.x >> 4;
  int j0 = blockIdx.x * TS, i0 = blockIdx.y * TS;
  float acc[4][4] = {};
  int lk = threadIdx.x & 15, lr = threadIdx.x >> 4;
  for (int k0 = 0; k0 < D_; k0 += KT) {
    #pragma unroll
    for (int it = 0; it < 4; ++it) {
      As[lr + 16 * it][lk] = A[(size_t)(i0 + lr + 16 * it) * D_ + k0 + lk];
      Bs[lr + 16 * it][lk] = A[(size_t)(j0 + lr + 16 * it) * D_ + k0 + lk];
    }
    __syncthreads();
    #pragma unroll
    for (int kk = 0; kk < KT; ++kk) {
      float a[4], bb[4];
      #pragma unroll
      for (int r = 0; r < 4; ++r) a[r] = As[ty * 4 + r][kk];
      #pragma unroll
      for (int c = 0; c < 4; ++c) bb[c] = Bs[tx * 4 + c][kk];
      #pragma unroll
      for (int r = 0; r < 4; ++r)
        #pragma unroll
        for (int c = 0; c < 4; ++c) acc[r][c] = fmaf(a[r], bb[c], acc[r][c]);
    }
    __syncthreads();
  }
  #pragma unroll
  for (int r = 0; r < 4; ++r) {
    float4 v = make_float4(acc[r][0]*SCALE_QK, acc[r][1]*SCALE_QK,
                           acc[r][2]*SCALE_QK, acc[r][3]*SCALE_QK);
    *reinterpret_cast<float4*>(&C[(size_t)(i0 + ty*4 + r) * SQ + j0 + tx*4]) = v;
  }
}

// ---------------- softmax rows in place ----------------
__global__ __launch_bounds__(256) void k_softmax(float* __restrict__ sc) {
  float* row = sc + (size_t)blockIdx.z * SQ * SQ + (size_t)blockIdx.x * SQ;
  int tid = threadIdx.x;
  __shared__ float red[8];
  float m = -1e30f;
  for (int j = tid; j < SQ; j += 256) m = fmaxf(m, row[j]);
  #pragma unroll
  for (int o = 32; o > 0; o >>= 1) m = fmaxf(m, __shfl_down(m, o));
  if ((tid & 63) == 0) red[tid >> 6] = m;
  __syncthreads();
  m = fmaxf(fmaxf(red[0], red[1]), fmaxf(red[2], red[3]));
  __syncthreads();
  float ssum = 0.f;
  for (int j = tid; j < SQ; j += 256) { float e = expf(row[j] - m); row[j] = e; ssum += e; }
  #pragma unroll
  for (int o = 32; o > 0; o >>= 1) ssum += __shfl_down(ssum, o);
  if ((tid & 63) == 0) red[4 + (tid >> 6)] = ssum;
  __syncthreads();
  float inv = 1.0f / (red[4] + red[5] + red[6] + red[7]);
  for (int j = tid; j < SQ; j += 256) row[j] *= inv;
}

// ---------------- attn_out = P @ X (fp32 path) ----------------
__global__ __launch_bounds__(256) void k_attn(const float* __restrict__ x,
                                              const float* __restrict__ sc,
                                              float* __restrict__ attn,
                                              int b_base, int x_full) {
  int z = blockIdx.z;
  size_t boff = (size_t)(x_full ? (b_base + z) : 0) * SQ * D_;
  const float* X = x + boff;
  const float* P = sc + (size_t)z * SQ * SQ;
  float* O = attn + (x_full ? boff : (size_t)0);
  __shared__ float Ps[TS][KT + 1];
  __shared__ float Xs[KT][TS];
  int tx = threadIdx.x & 15, ty = threadIdx.x >> 4;
  int j0 = blockIdx.x * TS, i0 = blockIdx.y * TS;
  float acc[4][4] = {};
  int lk = threadIdx.x & 15, lr = threadIdx.x >> 4;
  int lc = threadIdx.x & 63, lrow = threadIdx.x >> 6;
  for (int k0 = 0; k0 < SQ; k0 += KT) {
    #pragma unroll
    for (int it = 0; it < 4; ++it)
      Ps[lr + 16 * it][lk] = P[(size_t)(i0 + lr + 16 * it) * SQ + k0 + lk];
    #pragma unroll
    for (int it = 0; it < 4; ++it)
      Xs[lrow + 4 * it][lc] = X[(size_t)(k0 + lrow + 4 * it) * D_ + j0 + lc];
    __syncthreads();
    #pragma unroll
    for (int kk = 0; kk < KT; ++kk) {
      float a[4], bb[4];
      #pragma unroll
      for (int r = 0; r < 4; ++r) a[r] = Ps[ty * 4 + r][kk];
      #pragma unroll
      for (int c = 0; c < 4; ++c) bb[c] = Xs[kk][tx * 4 + c];
      #pragma unroll
      for (int r = 0; r < 4; ++r)
        #pragma unroll
        for (int c = 0; c < 4; ++c) acc[r][c] = fmaf(a[r], bb[c], acc[r][c]);
    }
    __syncthreads();
  }
  #pragma unroll
  for (int r = 0; r < 4; ++r) {
    float4 v = make_float4(acc[r][0], acc[r][1], acc[r][2], acc[r][3]);
    *reinterpret_cast<float4*>(&O[(size_t)(i0 + ty*4 + r) * D_ + j0 + tx*4]) = v;
  }
}

// ---------------- LN1 -> fp32 q (slow path) ----------------
__global__ __launch_bounds__(256) void k_ln1(const float* __restrict__ x,
                                             const float* __restrict__ attn,
                                             const float* __restrict__ g,
                                             const float* __restrict__ be,
                                             float* __restrict__ qout) {
  size_t base = (size_t)blockIdx.x * D_;
  int tid = threadIdx.x;
  __shared__ float rl[8];
  float v0 = x[base + tid] + attn[base + tid];
  float v1 = x[base + tid + 256] + attn[base + tid + 256];
  float s = v0 + v1, sq = v0 * v0 + v1 * v1;
  #pragma unroll
  for (int o = 32; o > 0; o >>= 1) { s += __shfl_down(s, o); sq += __shfl_down(sq, o); }
  int lane = tid & 63, wid = tid >> 6;
  if (lane == 0) { rl[wid] = s; rl[4 + wid] = sq; }
  __syncthreads();
  s = rl[0] + rl[1] + rl[2] + rl[3];
  sq = rl[4] + rl[5] + rl[6] + rl[7];
  float mean = s * (1.0f / 512.0f);
  float var = sq * (1.0f / 512.0f) - mean * mean;
  float rstd = rsqrtf(var + 1e-5f);
  qout[base + tid]       = (v0 - mean) * rstd * g[tid] + be[tid];
  qout[base + tid + 256] = (v1 - mean) * rstd * g[tid + 256] + be[tid + 256];
}

// ---------------- LN1 -> bf16 q (fast path) ----------------
__global__ __launch_bounds__(256) void k_ln1b(const float* __restrict__ x,
                                              const float* __restrict__ attn,
                                              const float* __restrict__ g,
                                              const float* __restrict__ be,
                                              ushort_t* __restrict__ qbf) {
  size_t base = (size_t)blockIdx.x * D_;
  int tid = threadIdx.x;
  __shared__ float rl[8];
  float v0 = x[base + tid] + attn[base + tid];
  float v1 = x[base + tid + 256] + attn[base + tid + 256];
  float s = v0 + v1, sq = v0 * v0 + v1 * v1;
  #pragma unroll
  for (int o = 32; o > 0; o >>= 1) { s += __shfl_down(s, o); sq += __shfl_down(sq, o); }
  int lane = tid & 63, wid = tid >> 6;
  if (lane == 0) { rl[wid] = s; rl[4 + wid] = sq; }
  __syncthreads();
  s = rl[0] + rl[1] + rl[2] + rl[3];
  sq = rl[4] + rl[5] + rl[6] + rl[7];
  float mean = s * (1.0f / 512.0f);
  float var = sq * (1.0f / 512.0f) - mean * mean;
  float rstd = rsqrtf(var + 1e-5f);
  qbf[base + tid]       = f2bfu((v0 - mean) * rstd * g[tid] + be[tid]);
  qbf[base + tid + 256] = f2bfu((v1 - mean) * rstd * g[tid + 256] + be[tid + 256]);
}

// ---- cast + transpose weights: W[K][N] fp32 -> Wt[N][K] bf16 ----
__global__ __launch_bounds__(256) void k_wt(const float* __restrict__ W,
                                            ushort_t* __restrict__ Wt,
                                            int K, int N) {
  __shared__ ushort_t tile[64][65];
  int n0 = blockIdx.x * 64, k0 = blockIdx.y * 64;
  for (int i = threadIdx.x; i < 4096; i += 256) {
    int kk = i >> 6, nn = i & 63;
    tile[nn][kk] = f2bfu(W[(size_t)(k0 + kk) * N + n0 + nn]);
  }
  __syncthreads();
  for (int i = threadIdx.x; i < 4096; i += 256) {
    int nn = i >> 6, kk = i & 63;
    Wt[(size_t)(n0 + nn) * K + k0 + kk] = tile[nn][kk];
  }
}

// ---- bf16 MFMA GEMM: C[M,N] = A[M,K] @ Bt[N,K]^T (+bias). MODE 0: gelu->bf16, 1: f32 ----
template<int MODE>
__global__ __launch_bounds__(256) void k_gemm(const ushort_t* __restrict__ A,
                                              const ushort_t* __restrict__ Bt,
                                              const float* __restrict__ bias,
                                              void* __restrict__ Cout,
                                              int M, int K, int N) {
  __shared__ ushort_t As[128][40];
  __shared__ ushort_t Bs[128][40];
  const int tid = threadIdx.x;
  const int m0 = blockIdx.y * 128, n0 = blockIdx.x * 128;
  const int w = tid >> 6, lane = tid & 63;
  const int wr = w >> 1, wc = w & 1;
  const int l15 = lane & 15, quad = lane >> 4;
  const int srow = tid >> 1, shalf = tid & 1;

  f32x4 acc[4][4];
  #pragma unroll
  for (int nj = 0; nj < 4; ++nj) {
    float bv = bias[n0 + wc * 64 + nj * 16 + l15];
    #pragma unroll
    for (int mi = 0; mi < 4; ++mi) acc[mi][nj] = (f32x4){bv, bv, bv, bv};
  }

  for (int k0 = 0; k0 < K; k0 += 32) {
    const ushort_t* ga = A  + (size_t)(m0 + srow) * K + k0 + shalf * 16;
    const ushort_t* gb = Bt + (size_t)(n0 + srow) * K + k0 + shalf * 16;
    uint4 va0 = *reinterpret_cast<const uint4*>(ga);
    uint4 va1 = *reinterpret_cast<const uint4*>(ga + 8);
    uint4 vb0 = *reinterpret_cast<const uint4*>(gb);
    uint4 vb1 = *reinterpret_cast<const uint4*>(gb + 8);
    __syncthreads();
    *reinterpret_cast<uint4*>(&As[srow][shalf * 16])     = va0;
    *reinterpret_cast<uint4*>(&As[srow][shalf * 16 + 8]) = va1;
    *reinterpret_cast<uint4*>(&Bs[srow][shalf * 16])     = vb0;
    *reinterpret_cast<uint4*>(&Bs[srow][shalf * 16 + 8]) = vb1;
    __syncthreads();
    bf16x8 af[4], bfv[4];
    #pragma unroll
    for (int mi = 0; mi < 4; ++mi)
      af[mi] = *reinterpret_cast<const bf16x8*>(&As[wr * 64 + mi * 16 + l15][quad * 8]);
    #pragma unroll
    for (int nj = 0; nj < 4; ++nj)
      bfv[nj] = *reinterpret_cast<const bf16x8*>(&Bs[wc * 64 + nj * 16 + l15][quad * 8]);
    #pragma unroll
    for (int mi = 0; mi < 4; ++mi)
      #pragma unroll
      for (int nj = 0; nj < 4; ++nj)
        acc[mi][nj] = __builtin_amdgcn_mfma_f32_16x16x32_bf16(af[mi], bfv[nj], acc[mi][nj], 0, 0, 0);
  }

  #pragma unroll
  for (int mi = 0; mi < 4; ++mi)
    #pragma unroll
    for (int nj = 0; nj < 4; ++nj) {
      int gc = n0 + wc * 64 + nj * 16 + l15;
      #pragma unroll
      for (int r = 0; r < 4; ++r) {
        int gr = m0 + wr * 64 + mi * 16 + quad * 4 + r;
        float v = acc[mi][nj][r];
        if (MODE == 0) {
          v = 0.5f * v * (1.0f + erff(v * 0.70710678118654752f));
          ((__hip_bfloat16*)Cout)[(size_t)gr * N + gc] = __float2bfloat16(v);
        } else {
          ((float*)Cout)[(size_t)gr * N + gc] = v;
        }
      }
    }
}

// ---- LN3: out = transpose(LN(qbf + y)) ----
__global__ __launch_bounds__(256) void k_ln3(const float* __restrict__ y,
                                             const ushort_t* __restrict__ qbf,
                                             const float* __restrict__ g3,
                                             const float* __restrict__ be3,
                                             float* __restrict__ out) {
  int row = blockIdx.x;
  size_t base = (size_t)row * D_;
  int tid = threadIdx.x;
  __shared__ float rl[8];
  float v0 = y[base + tid] + bfu2f(qbf[base + tid]);
  float v1 = y[base + tid + 256] + bfu2f(qbf[base + tid + 256]);
  float s = v0 + v1, sq = v0 * v0 + v1 * v1;
  #pragma unroll
  for (int o = 32; o > 0; o >>= 1) { s += __shfl_down(s, o); sq += __shfl_down(sq, o); }
  int lane = tid & 63, wid = tid >> 6;
  if (lane == 0) { rl[wid] = s; rl[4 + wid] = sq; }
  __syncthreads();
  s = rl[0] + rl[1] + rl[2] + rl[3];
  sq = rl[4] + rl[5] + rl[6] + rl[7];
  float mean = s * (1.0f / 512.0f);
  float var = sq * (1.0f / 512.0f) - mean * mean;
  float rstd = rsqrtf(var + 1e-5f);
  int b = row / SQ, tt = row - b * SQ;
  int si = tt >> 3, l = tt & 7;
  size_t ob = (((size_t)(b * S_ + si) * D_) << 3) + l;
  out[ob + ((size_t)tid << 3)]         = (v0 - mean) * rstd * g3[tid] + be3[tid];
  out[ob + ((size_t)(tid + 256) << 3)] = (v1 - mean) * rstd * g3[tid + 256] + be3[tid + 256];
}

// ---------------- slow-path FFN (unchanged, fp32) ----------------
__global__ __launch_bounds__(256, 2) void k_ffn(
    const float* __restrict__ q,
    const float* __restrict__ W1, const float* __restrict__ b1,
    const float* __restrict__ W2, const float* __restrict__ b2,
    const float* __restrict__ g3, const float* __restrict__ be3,
    float* __restrict__ out, int row_base)
{
  __shared__ float qs[8][D_];
  __shared__ float mid[8][H_];
  const int tid = threadIdx.x;
  const int row0 = blockIdx.x * 8;
  for (int idx = tid; idx < 8 * D_; idx += 256)
    qs[idx >> 9][idx & (D_ - 1)] = q[(size_t)row0 * D_ + idx];
  __syncthreads();
  float acc[8][8];
  {
    float4 bA = *reinterpret_cast<const float4*>(b1 + (tid << 3));
    float4 bB = *reinterpret_cast<const float4*>(b1 + (tid << 3) + 4);
    float bv[8] = {bA.x, bA.y, bA.z, bA.w, bB.x, bB.y, bB.z, bB.w};
    #pragma unroll
    for (int jj = 0; jj < 8; ++jj)
      #pragma unroll
      for (int r = 0; r < 8; ++r) acc[jj][r] = bv[jj];
  }
  for (int k4 = 0; k4 < D_ / 4; ++k4) {
    float4 qv[8];
    #pragma unroll
    for (int r = 0; r < 8; ++r)
      qv[r] = *reinterpret_cast<const float4*>(&qs[r][k4 << 2]);
    #pragma unroll
    for (int kk = 0; kk < 4; ++kk) {
      const int k = (k4 << 2) + kk;
      float4 wA = *reinterpret_cast<const float4*>(W1 + (size_t)k * H_ + (tid << 3));
      float4 wB = *reinterpret_cast<const float4*>(W1 + (size_t)k * H_ + (tid << 3) + 4);
      float wv[8] = {wA.x, wA.y, wA.z, wA.w, wB.x, wB.y, wB.z, wB.w};
      #pragma unroll
      for (int r = 0; r < 8; ++r) {
        float qk = (kk == 0) ? qv[r].x : (kk == 1) ? qv[r].y : (kk == 2) ? qv[r].z : qv[r].w;
        #pragma unroll
        for (int jj = 0; jj < 8; ++jj) acc[jj][r] = fmaf(qk, wv[jj], acc[jj][r]);
      }
    }
  }
  #pragma unroll
  for (int jj = 0; jj < 8; ++jj)
    #pragma unroll
    for (int r = 0; r < 8; ++r) {
      float v = acc[jj][r];
      mid[r][(tid << 3) + jj] = 0.5f * v * (1.0f + erff(v * 0.70710678118654752f));
    }
  __syncthreads();
  float acc2[8][2];
  {
    float b20 = b2[tid << 1], b21 = b2[(tid << 1) + 1];
    #pragma unroll
    for (int r = 0; r < 8; ++r) { acc2[r][0] = b20; acc2[r][1] = b21; }
  }
  for (int j4 = 0; j4 < H_ / 4; ++j4) {
    float4 mv[8];
    #pragma unroll
    for (int r = 0; r < 8; ++r)
      mv[r] = *reinterpret_cast<const float4*>(&mid[r][j4 << 2]);
    #pragma unroll
    for (int kk = 0; kk < 4; ++kk) {
      const int j = (j4 << 2) + kk;
      float2 wv = *reinterpret_cast<const float2*>(W2 + (size_t)j * D_ + (tid << 1));
      #pragma unroll
      for (int r = 0; r < 8; ++r) {
        float m = (kk == 0) ? mv[r].x : (kk == 1) ? mv[r].y : (kk == 2) ? mv[r].z : mv[r].w;
        acc2[r][0] = fmaf(m, wv.x, acc2[r][0]);
        acc2[r][1] = fmaf(m, wv.y, acc2[r][1]);
      }
    }
  }
  __syncthreads();
  float* ys = &mid[0][0];
  #pragma unroll
  for (int r = 0; r < 8; ++r) {
    ys[r * D_ + (tid << 1)]     = qs[r][(tid << 1)]     + acc2[r][0];
    ys[r * D_ + (tid << 1) + 1] = qs[r][(tid << 1) + 1] + acc2[r][1];
  }
  __syncthreads();
  float g3a = g3[tid],  g3b = g3[tid + 256];
  float be3a = be3[tid], be3b = be3[tid + 256];
  float* rl = &qs[0][0];
  for (int r = 0; r < 8; ++r) {
    float v0 = ys[r * D_ + tid], v1 = ys[r * D_ + tid + 256];
    float s = v0 + v1, sq = v0 * v0 + v1 * v1;
    #pragma unroll
    for (int o = 32; o > 0; o >>= 1) { s += __shfl_down(s, o); sq += __shfl_down(sq, o); }
    int lane = tid & 63, wid = tid >> 6;
    if (lane == 0) { rl[wid] = s; rl[4 + wid] = sq; }
    __syncthreads();
    s = rl[0] + rl[1] + rl[2] + rl[3];
    sq = rl[4] + rl[5] + rl[6] + rl[7];
    __syncthreads();
    float mean = s * (1.0f / 512.0f);
    float var = sq * (1.0f / 512.0f) - mean * mean;
    float rstd = rsqrtf(var + 1e-5f);
    int t = row_base + row0 + r;
    int b = t / SQ, tt = t - b * SQ;
    int si = tt >> 3, l = tt & 7;
    size_t ob = (((size_t)(b * S_ + si) * D_) << 3) + l;
    out[ob + ((size_t)tid << 3)]         = (v0 - mean) * rstd * g3a + be3a;
    out[ob + ((size_t)(tid + 256) << 3)] = (v1 - mean) * rstd * g3b + be3b;
  }
}

extern "C" void kernel_launch(void* const* d_in, const int* in_sizes, int n_in,
                              void* d_out, int out_size, void* d_ws, size_t ws_size,
                              hipStream_t stream) {
  const float* lags   = (const float*)d_in[0];
  const float* gamma1 = (const float*)d_in[1];
  const float* beta1  = (const float*)d_in[2];
  const float* W1     = (const float*)d_in[3];
  const float* b1     = (const float*)d_in[4];
  const float* W2     = (const float*)d_in[5];
  const float* b2     = (const float*)d_in[6];
  const float* g3     = (const float*)d_in[7];
  const float* be3    = (const float*)d_in[8];
  float* out = (float*)d_out;

  float* ws = (float*)d_ws;
  const size_t NX  = (size_t)B_ * SQ * D_;   // 6,291,456
  const size_t NXB = (size_t)SQ * D_;
  const size_t NS  = (size_t)SQ * SQ;

  const size_t need_full = (3 * NX + 8 * NS) * sizeof(float);  // ~151 MB (proven available)

  if (ws_size >= need_full) {
    // ---- fast path layout (~130 MB) ----
    float* x    = ws;                       // 25.2 MB
    float* attn = x + NX;                   // 25.2 MB (reused as y after LN1)
    float* sc   = attn + NX;                // 75.5 MB scores region
    ushort_t* mid_bf = (ushort_t*)sc;                        // 50.3 MB (aliases dead sc)
    ushort_t* q_bf   = (ushort_t*)sc + (size_t)NROW * H_;    // 12.6 MB
    ushort_t* w1t = (ushort_t*)(sc + 8 * NS);                // 2 MB  [H_][D_]
    ushort_t* w2t = w1t + (size_t)H_ * D_;                   // 2 MB  [D_][H_]

    k_build_x<<<dim3((unsigned)(NX / 256)), 256, 0, stream>>>(lags, x, 0);
    k_wt<<<dim3(H_ / 64, D_ / 64), 256, 0, stream>>>(W1, w1t, D_, H_);
    k_wt<<<dim3(D_ / 64, H_ / 64), 256, 0, stream>>>(W2, w2t, H_, D_);
    k_scores<<<dim3(SQ / TS, SQ / TS, 8), 256, 0, stream>>>(x, sc, 0, 1);
    k_softmax<<<dim3(SQ, 1, 8), 256, 0, stream>>>(sc);
    k_attn<<<dim3(D_ / TS, SQ / TS, 8), 256, 0, stream>>>(x, sc, attn, 0, 1);
    k_ln1b<<<dim3(NROW), 256, 0, stream>>>(x, attn, gamma1, beta1, q_bf);
    // GEMM1: mid = gelu(q @ W1 + b1)   [12288 x 512] x [512 x 2048]
    k_gemm<0><<<dim3(H_ / 128, NROW / 128), 256, 0, stream>>>(q_bf, w1t, b1, mid_bf, NROW, D_, H_);
    // GEMM2: y = mid @ W2 + b2         [12288 x 2048] x [2048 x 512]  -> attn buffer
    k_gemm<1><<<dim3(D_ / 128, NROW / 128), 256, 0, stream>>>(mid_bf, w2t, b2, attn, NROW, H_, D_);
    k_ln3<<<dim3(NROW), 256, 0, stream>>>(attn, q_bf, g3, be3, out);
  } else {
    // ---- minimal-footprint fallback (fp32, per-batch) ----
    float* xb   = ws;
    float* sc   = xb + NXB;
    float* atb  = sc + NS;
    float* qb   = atb + NXB;
    for (int b = 0; b < B_; ++b) {
      k_build_x<<<dim3((unsigned)(NXB / 256)), 256, 0, stream>>>(lags, xb, b);
      k_scores<<<dim3(SQ / TS, SQ / TS, 1), 256, 0, stream>>>(xb, sc, b, 0);
      k_softmax<<<dim3(SQ, 1, 1), 256, 0, stream>>>(sc);
      k_attn<<<dim3(D_ / TS, SQ / TS, 1), 256, 0, stream>>>(xb, sc, atb, b, 0);
      k_ln1<<<dim3(SQ), 256, 0, stream>>>(xb, atb, gamma1, beta1, qb);
      k_ffn<<<dim3(SQ / 8), 256, 0, stream>>>(qb, W1, b1, W2, b2, g3, be3, out, b * SQ);
    }
  }
}

// Round 5
// 397.514 us; speedup vs baseline: 4.4093x; 2.5475x over previous
//
#include <hip/hip_runtime.h>
#include <hip/hip_bf16.h>
#include <math.h>

#define B_ 8
#define S_ 192
#define D_ 512
#define L_ 8
#define SQ 1536   // S_*L_
#define H_ 2048
#define NROW (B_*SQ)   // 12288
#define SCALE_QK 0.04419417382415922f  // 1/sqrt(512)

typedef unsigned short ushort_t;
typedef __attribute__((ext_vector_type(8))) short bf16x8;
typedef __attribute__((ext_vector_type(4))) float f32x4;

__device__ __forceinline__ float bfu2f(ushort_t u) { return __uint_as_float((unsigned)u << 16); }
__device__ __forceinline__ ushort_t f2bfu(float f) {
  __hip_bfloat16 h = __float2bfloat16(f);
  return *reinterpret_cast<ushort_t*>(&h);
}

// ---- build x rows: (B,s,d,L) fp32 -> x fp32 [NROW][D] + x_bf bf16 ----
__global__ __launch_bounds__(256) void k_build_x(const float* __restrict__ lags,
                                                 float* __restrict__ x,
                                                 ushort_t* __restrict__ x_bf, int b_base) {
  int idx = blockIdx.x * 256 + threadIdx.x;
  int k = idx & (D_ - 1);
  int r = idx >> 9;
  int b = b_base + r / SQ;
  int t = r - (r / SQ) * SQ;
  int si = t >> 3, l = t & 7;
  size_t src = (((size_t)(b * S_ + si) * D_ + k) << 3) + l;
  float v = lags[src];
  x[idx] = v;
  if (x_bf) x_bf[idx] = f2bfu(v);
}

// ---- 64x64 LDS transpose: x_bf [SQ][D] -> xT_bf [D][SQ], per batch z ----
__global__ __launch_bounds__(256) void k_xt(const ushort_t* __restrict__ x_bf,
                                            ushort_t* __restrict__ xT) {
  __shared__ ushort_t tile[64][65];
  int t0 = blockIdx.x * 64, d0 = blockIdx.y * 64;
  const ushort_t* X = x_bf + (size_t)blockIdx.z * SQ * D_;
  ushort_t* XT = xT + (size_t)blockIdx.z * SQ * D_;
  for (int i = threadIdx.x; i < 4096; i += 256) {
    int tt = i >> 6, dd = i & 63;
    tile[dd][tt] = X[(size_t)(t0 + tt) * D_ + d0 + dd];
  }
  __syncthreads();
  for (int i = threadIdx.x; i < 4096; i += 256) {
    int dd = i >> 6, tt = i & 63;
    XT[(size_t)(d0 + dd) * SQ + t0 + tt] = tile[dd][tt];
  }
}

// ---- cast + transpose weights: W[K][N] fp32 -> Wt[N][K] bf16 ----
__global__ __launch_bounds__(256) void k_wt(const float* __restrict__ W,
                                            ushort_t* __restrict__ Wt,
                                            int K, int N) {
  __shared__ ushort_t tile[64][65];
  int n0 = blockIdx.x * 64, k0 = blockIdx.y * 64;
  for (int i = threadIdx.x; i < 4096; i += 256) {
    int kk = i >> 6, nn = i & 63;
    tile[nn][kk] = f2bfu(W[(size_t)(k0 + kk) * N + n0 + nn]);
  }
  __syncthreads();
  for (int i = threadIdx.x; i < 4096; i += 256) {
    int nn = i >> 6, kk = i & 63;
    Wt[(size_t)(n0 + nn) * K + k0 + kk] = tile[nn][kk];
  }
}

// ---- bf16 MFMA GEMM: C[M,N] = A[M,K] @ Bt[N,K]^T
// MODE 0: +bias, gelu -> bf16 | 1: +bias -> f32 | 2: *scale -> bf16 | 3: -> f32
template<int MODE>
__global__ __launch_bounds__(256) void k_gemm(const ushort_t* __restrict__ A,
                                              const ushort_t* __restrict__ Bt,
                                              const float* __restrict__ bias,
                                              void* __restrict__ Cout,
                                              int M, int K, int N,
                                              size_t sAz, size_t sBz, size_t sCz,
                                              float scale) {
  A  += (size_t)blockIdx.z * sAz;
  Bt += (size_t)blockIdx.z * sBz;
  __shared__ ushort_t As[128][40];
  __shared__ ushort_t Bs[128][40];
  const int tid = threadIdx.x;
  const int m0 = blockIdx.y * 128, n0 = blockIdx.x * 128;
  const int w = tid >> 6, lane = tid & 63;
  const int wr = w >> 1, wc = w & 1;
  const int l15 = lane & 15, quad = lane >> 4;
  const int srow = tid >> 1, shalf = tid & 1;

  f32x4 acc[4][4];
  if (MODE <= 1) {
    #pragma unroll
    for (int nj = 0; nj < 4; ++nj) {
      float bv = bias[n0 + wc * 64 + nj * 16 + l15];
      #pragma unroll
      for (int mi = 0; mi < 4; ++mi) acc[mi][nj] = (f32x4){bv, bv, bv, bv};
    }
  } else {
    #pragma unroll
    for (int nj = 0; nj < 4; ++nj)
      #pragma unroll
      for (int mi = 0; mi < 4; ++mi) acc[mi][nj] = (f32x4){0.f, 0.f, 0.f, 0.f};
  }

  for (int k0 = 0; k0 < K; k0 += 32) {
    const ushort_t* ga = A  + (size_t)(m0 + srow) * K + k0 + shalf * 16;
    const ushort_t* gb = Bt + (size_t)(n0 + srow) * K + k0 + shalf * 16;
    uint4 va0 = *reinterpret_cast<const uint4*>(ga);
    uint4 va1 = *reinterpret_cast<const uint4*>(ga + 8);
    uint4 vb0 = *reinterpret_cast<const uint4*>(gb);
    uint4 vb1 = *reinterpret_cast<const uint4*>(gb + 8);
    __syncthreads();
    *reinterpret_cast<uint4*>(&As[srow][shalf * 16])     = va0;
    *reinterpret_cast<uint4*>(&As[srow][shalf * 16 + 8]) = va1;
    *reinterpret_cast<uint4*>(&Bs[srow][shalf * 16])     = vb0;
    *reinterpret_cast<uint4*>(&Bs[srow][shalf * 16 + 8]) = vb1;
    __syncthreads();
    bf16x8 af[4], bfv[4];
    #pragma unroll
    for (int mi = 0; mi < 4; ++mi)
      af[mi] = *reinterpret_cast<const bf16x8*>(&As[wr * 64 + mi * 16 + l15][quad * 8]);
    #pragma unroll
    for (int nj = 0; nj < 4; ++nj)
      bfv[nj] = *reinterpret_cast<const bf16x8*>(&Bs[wc * 64 + nj * 16 + l15][quad * 8]);
    #pragma unroll
    for (int mi = 0; mi < 4; ++mi)
      #pragma unroll
      for (int nj = 0; nj < 4; ++nj)
        acc[mi][nj] = __builtin_amdgcn_mfma_f32_16x16x32_bf16(af[mi], bfv[nj], acc[mi][nj], 0, 0, 0);
  }

  ushort_t* Cb = (ushort_t*)Cout + (size_t)blockIdx.z * sCz;
  float*    Cf = (float*)Cout    + (size_t)blockIdx.z * sCz;
  #pragma unroll
  for (int mi = 0; mi < 4; ++mi)
    #pragma unroll
    for (int nj = 0; nj < 4; ++nj) {
      int gc = n0 + wc * 64 + nj * 16 + l15;
      #pragma unroll
      for (int r = 0; r < 4; ++r) {
        int gr = m0 + wr * 64 + mi * 16 + quad * 4 + r;
        float v = acc[mi][nj][r];
        if (MODE == 0) {
          v = 0.5f * v * (1.0f + erff(v * 0.70710678118654752f));
          Cb[(size_t)gr * N + gc] = f2bfu(v);
        } else if (MODE == 1) {
          Cf[(size_t)gr * N + gc] = v;
        } else if (MODE == 2) {
          Cb[(size_t)gr * N + gc] = f2bfu(v * scale);
        } else {
          Cf[(size_t)gr * N + gc] = v;
        }
      }
    }
}

// ---- softmax rows in place, bf16 storage, fp32 math ----
__global__ __launch_bounds__(256) void k_softmax_bf(ushort_t* __restrict__ sc) {
  ushort_t* row = sc + (size_t)blockIdx.z * SQ * SQ + (size_t)blockIdx.x * SQ;
  int tid = threadIdx.x;
  __shared__ float red[8];
  float v[SQ / 256];
  float m = -1e30f;
  #pragma unroll
  for (int k = 0; k < SQ / 256; ++k) { v[k] = bfu2f(row[tid + k * 256]); m = fmaxf(m, v[k]); }
  #pragma unroll
  for (int o = 32; o > 0; o >>= 1) m = fmaxf(m, __shfl_down(m, o));
  if ((tid & 63) == 0) red[tid >> 6] = m;
  __syncthreads();
  m = fmaxf(fmaxf(red[0], red[1]), fmaxf(red[2], red[3]));
  __syncthreads();
  float ssum = 0.f;
  #pragma unroll
  for (int k = 0; k < SQ / 256; ++k) { v[k] = expf(v[k] - m); ssum += v[k]; }
  #pragma unroll
  for (int o = 32; o > 0; o >>= 1) ssum += __shfl_down(ssum, o);
  if ((tid & 63) == 0) red[4 + (tid >> 6)] = ssum;
  __syncthreads();
  float inv = 1.0f / (red[4] + red[5] + red[6] + red[7]);
  #pragma unroll
  for (int k = 0; k < SQ / 256; ++k) row[tid + k * 256] = f2bfu(v[k] * inv);
}

// ---- LN1 -> bf16 q ----
__global__ __launch_bounds__(256) void k_ln1b(const float* __restrict__ x,
                                              const float* __restrict__ attn,
                                              const float* __restrict__ g,
                                              const float* __restrict__ be,
                                              ushort_t* __restrict__ qbf) {
  size_t base = (size_t)blockIdx.x * D_;
  int tid = threadIdx.x;
  __shared__ float rl[8];
  float v0 = x[base + tid] + attn[base + tid];
  float v1 = x[base + tid + 256] + attn[base + tid + 256];
  float s = v0 + v1, sq = v0 * v0 + v1 * v1;
  #pragma unroll
  for (int o = 32; o > 0; o >>= 1) { s += __shfl_down(s, o); sq += __shfl_down(sq, o); }
  int lane = tid & 63, wid = tid >> 6;
  if (lane == 0) { rl[wid] = s; rl[4 + wid] = sq; }
  __syncthreads();
  s = rl[0] + rl[1] + rl[2] + rl[3];
  sq = rl[4] + rl[5] + rl[6] + rl[7];
  float mean = s * (1.0f / 512.0f);
  float var = sq * (1.0f / 512.0f) - mean * mean;
  float rstd = rsqrtf(var + 1e-5f);
  qbf[base + tid]       = f2bfu((v0 - mean) * rstd * g[tid] + be[tid]);
  qbf[base + tid + 256] = f2bfu((v1 - mean) * rstd * g[tid + 256] + be[tid + 256]);
}

// ---- LN3: out = transpose(LN(qbf + y)) ----
__global__ __launch_bounds__(256) void k_ln3(const float* __restrict__ y,
                                             const ushort_t* __restrict__ qbf,
                                             const float* __restrict__ g3,
                                             const float* __restrict__ be3,
                                             float* __restrict__ out) {
  int row = blockIdx.x;
  size_t base = (size_t)row * D_;
  int tid = threadIdx.x;
  __shared__ float rl[8];
  float v0 = y[base + tid] + bfu2f(qbf[base + tid]);
  float v1 = y[base + tid + 256] + bfu2f(qbf[base + tid + 256]);
  float s = v0 + v1, sq = v0 * v0 + v1 * v1;
  #pragma unroll
  for (int o = 32; o > 0; o >>= 1) { s += __shfl_down(s, o); sq += __shfl_down(sq, o); }
  int lane = tid & 63, wid = tid >> 6;
  if (lane == 0) { rl[wid] = s; rl[4 + wid] = sq; }
  __syncthreads();
  s = rl[0] + rl[1] + rl[2] + rl[3];
  sq = rl[4] + rl[5] + rl[6] + rl[7];
  float mean = s * (1.0f / 512.0f);
  float var = sq * (1.0f / 512.0f) - mean * mean;
  float rstd = rsqrtf(var + 1e-5f);
  int b = row / SQ, tt = row - b * SQ;
  int si = tt >> 3, l = tt & 7;
  size_t ob = (((size_t)(b * S_ + si) * D_) << 3) + l;
  out[ob + ((size_t)tid << 3)]         = (v0 - mean) * rstd * g3[tid] + be3[tid];
  out[ob + ((size_t)(tid + 256) << 3)] = (v1 - mean) * rstd * g3[tid + 256] + be3[tid + 256];
}

// ================= slow-path fp32 kernels (fallback only) =================
#define TS 64
#define KT 16
__global__ __launch_bounds__(256) void k_scores(const float* __restrict__ x,
                                                float* __restrict__ sc, int b_base) {
  const float* A = x;
  float* C = sc;
  __shared__ float As[TS][KT + 1];
  __shared__ float Bs[TS][KT + 1];
  int tx = threadIdx.x & 15, ty = threadIdx.x >> 4;
  int j0 = blockIdx.x * TS, i0 = blockIdx.y * TS;
  float acc[4][4] = {};
  int lk = threadIdx.x & 15, lr = threadIdx.x >> 4;
  for (int k0 = 0; k0 < D_; k0 += KT) {
    #pragma unroll
    for (int it = 0; it < 4; ++it) {
      As[lr + 16 * it][lk] = A[(size_t)(i0 + lr + 16 * it) * D_ + k0 + lk];
      Bs[lr + 16 * it][lk] = A[(size_t)(j0 + lr + 16 * it) * D_ + k0 + lk];
    }
    __syncthreads();
    #pragma unroll
    for (int kk = 0; kk < KT; ++kk) {
      float a[4], bb[4];
      #pragma unroll
      for (int r = 0; r < 4; ++r) a[r] = As[ty * 4 + r][kk];
      #pragma unroll
      for (int c = 0; c < 4; ++c) bb[c] = Bs[tx * 4 + c][kk];
      #pragma unroll
      for (int r = 0; r < 4; ++r)
        #pragma unroll
        for (int c = 0; c < 4; ++c) acc[r][c] = fmaf(a[r], bb[c], acc[r][c]);
    }
    __syncthreads();
  }
  #pragma unroll
  for (int r = 0; r < 4; ++r) {
    float4 v = make_float4(acc[r][0]*SCALE_QK, acc[r][1]*SCALE_QK,
                           acc[r][2]*SCALE_QK, acc[r][3]*SCALE_QK);
    *reinterpret_cast<float4*>(&C[(size_t)(i0 + ty*4 + r) * SQ + j0 + tx*4]) = v;
  }
}

__global__ __launch_bounds__(256) void k_softmax(float* __restrict__ sc) {
  float* row = sc + (size_t)blockIdx.x * SQ;
  int tid = threadIdx.x;
  __shared__ float red[8];
  float m = -1e30f;
  for (int j = tid; j < SQ; j += 256) m = fmaxf(m, row[j]);
  #pragma unroll
  for (int o = 32; o > 0; o >>= 1) m = fmaxf(m, __shfl_down(m, o));
  if ((tid & 63) == 0) red[tid >> 6] = m;
  __syncthreads();
  m = fmaxf(fmaxf(red[0], red[1]), fmaxf(red[2], red[3]));
  __syncthreads();
  float ssum = 0.f;
  for (int j = tid; j < SQ; j += 256) { float e = expf(row[j] - m); row[j] = e; ssum += e; }
  #pragma unroll
  for (int o = 32; o > 0; o >>= 1) ssum += __shfl_down(ssum, o);
  if ((tid & 63) == 0) red[4 + (tid >> 6)] = ssum;
  __syncthreads();
  float inv = 1.0f / (red[4] + red[5] + red[6] + red[7]);
  for (int j = tid; j < SQ; j += 256) row[j] *= inv;
}

__global__ __launch_bounds__(256) void k_attn(const float* __restrict__ x,
                                              const float* __restrict__ sc,
                                              float* __restrict__ attn) {
  const float* X = x;
  const float* P = sc;
  float* O = attn;
  __shared__ float Ps[TS][KT + 1];
  __shared__ float Xs[KT][TS];
  int tx = threadIdx.x & 15, ty = threadIdx.x >> 4;
  int j0 = blockIdx.x * TS, i0 = blockIdx.y * TS;
  float acc[4][4] = {};
  int lk = threadIdx.x & 15, lr = threadIdx.x >> 4;
  int lc = threadIdx.x & 63, lrow = threadIdx.x >> 6;
  for (int k0 = 0; k0 < SQ; k0 += KT) {
    #pragma unroll
    for (int it = 0; it < 4; ++it)
      Ps[lr + 16 * it][lk] = P[(size_t)(i0 + lr + 16 * it) * SQ + k0 + lk];
    #pragma unroll
    for (int it = 0; it < 4; ++it)
      Xs[lrow + 4 * it][lc] = X[(size_t)(k0 + lrow + 4 * it) * D_ + j0 + lc];
    __syncthreads();
    #pragma unroll
    for (int kk = 0; kk < KT; ++kk) {
      float a[4], bb[4];
      #pragma unroll
      for (int r = 0; r < 4; ++r) a[r] = Ps[ty * 4 + r][kk];
      #pragma unroll
      for (int c = 0; c < 4; ++c) bb[c] = Xs[kk][tx * 4 + c];
      #pragma unroll
      for (int r = 0; r < 4; ++r)
        #pragma unroll
        for (int c = 0; c < 4; ++c) acc[r][c] = fmaf(a[r], bb[c], acc[r][c]);
    }
    __syncthreads();
  }
  #pragma unroll
  for (int r = 0; r < 4; ++r) {
    float4 v = make_float4(acc[r][0], acc[r][1], acc[r][2], acc[r][3]);
    *reinterpret_cast<float4*>(&O[(size_t)(i0 + ty*4 + r) * D_ + j0 + tx*4]) = v;
  }
}

__global__ __launch_bounds__(256) void k_ln1(const float* __restrict__ x,
                                             const float* __restrict__ attn,
                                             const float* __restrict__ g,
                                             const float* __restrict__ be,
                                             float* __restrict__ qout) {
  size_t base = (size_t)blockIdx.x * D_;
  int tid = threadIdx.x;
  __shared__ float rl[8];
  float v0 = x[base + tid] + attn[base + tid];
  float v1 = x[base + tid + 256] + attn[base + tid + 256];
  float s = v0 + v1, sq = v0 * v0 + v1 * v1;
  #pragma unroll
  for (int o = 32; o > 0; o >>= 1) { s += __shfl_down(s, o); sq += __shfl_down(sq, o); }
  int lane = tid & 63, wid = tid >> 6;
  if (lane == 0) { rl[wid] = s; rl[4 + wid] = sq; }
  __syncthreads();
  s = rl[0] + rl[1] + rl[2] + rl[3];
  sq = rl[4] + rl[5] + rl[6] + rl[7];
  float mean = s * (1.0f / 512.0f);
  float var = sq * (1.0f / 512.0f) - mean * mean;
  float rstd = rsqrtf(var + 1e-5f);
  qout[base + tid]       = (v0 - mean) * rstd * g[tid] + be[tid];
  qout[base + tid + 256] = (v1 - mean) * rstd * g[tid + 256] + be[tid + 256];
}

__global__ __launch_bounds__(256, 2) void k_ffn(
    const float* __restrict__ q,
    const float* __restrict__ W1, const float* __restrict__ b1,
    const float* __restrict__ W2, const float* __restrict__ b2,
    const float* __restrict__ g3, const float* __restrict__ be3,
    float* __restrict__ out, int row_base)
{
  __shared__ float qs[8][D_];
  __shared__ float mid[8][H_];
  const int tid = threadIdx.x;
  const int row0 = blockIdx.x * 8;
  for (int idx = tid; idx < 8 * D_; idx += 256)
    qs[idx >> 9][idx & (D_ - 1)] = q[(size_t)row0 * D_ + idx];
  __syncthreads();
  float acc[8][8];
  {
    float4 bA = *reinterpret_cast<const float4*>(b1 + (tid << 3));
    float4 bB = *reinterpret_cast<const float4*>(b1 + (tid << 3) + 4);
    float bv[8] = {bA.x, bA.y, bA.z, bA.w, bB.x, bB.y, bB.z, bB.w};
    #pragma unroll
    for (int jj = 0; jj < 8; ++jj)
      #pragma unroll
      for (int r = 0; r < 8; ++r) acc[jj][r] = bv[jj];
  }
  for (int k4 = 0; k4 < D_ / 4; ++k4) {
    float4 qv[8];
    #pragma unroll
    for (int r = 0; r < 8; ++r)
      qv[r] = *reinterpret_cast<const float4*>(&qs[r][k4 << 2]);
    #pragma unroll
    for (int kk = 0; kk < 4; ++kk) {
      const int k = (k4 << 2) + kk;
      float4 wA = *reinterpret_cast<const float4*>(W1 + (size_t)k * H_ + (tid << 3));
      float4 wB = *reinterpret_cast<const float4*>(W1 + (size_t)k * H_ + (tid << 3) + 4);
      float wv[8] = {wA.x, wA.y, wA.z, wA.w, wB.x, wB.y, wB.z, wB.w};
      #pragma unroll
      for (int r = 0; r < 8; ++r) {
        float qk = (kk == 0) ? qv[r].x : (kk == 1) ? qv[r].y : (kk == 2) ? qv[r].z : qv[r].w;
        #pragma unroll
        for (int jj = 0; jj < 8; ++jj) acc[jj][r] = fmaf(qk, wv[jj], acc[jj][r]);
      }
    }
  }
  #pragma unroll
  for (int jj = 0; jj < 8; ++jj)
    #pragma unroll
    for (int r = 0; r < 8; ++r) {
      float v = acc[jj][r];
      mid[r][(tid << 3) + jj] = 0.5f * v * (1.0f + erff(v * 0.70710678118654752f));
    }
  __syncthreads();
  float acc2[8][2];
  {
    float b20 = b2[tid << 1], b21 = b2[(tid << 1) + 1];
    #pragma unroll
    for (int r = 0; r < 8; ++r) { acc2[r][0] = b20; acc2[r][1] = b21; }
  }
  for (int j4 = 0; j4 < H_ / 4; ++j4) {
    float4 mv[8];
    #pragma unroll
    for (int r = 0; r < 8; ++r)
      mv[r] = *reinterpret_cast<const float4*>(&mid[r][j4 << 2]);
    #pragma unroll
    for (int kk = 0; kk < 4; ++kk) {
      const int j = (j4 << 2) + kk;
      float2 wv = *reinterpret_cast<const float2*>(W2 + (size_t)j * D_ + (tid << 1));
      #pragma unroll
      for (int r = 0; r < 8; ++r) {
        float m = (kk == 0) ? mv[r].x : (kk == 1) ? mv[r].y : (kk == 2) ? mv[r].z : mv[r].w;
        acc2[r][0] = fmaf(m, wv.x, acc2[r][0]);
        acc2[r][1] = fmaf(m, wv.y, acc2[r][1]);
      }
    }
  }
  __syncthreads();
  float* ys = &mid[0][0];
  #pragma unroll
  for (int r = 0; r < 8; ++r) {
    ys[r * D_ + (tid << 1)]     = qs[r][(tid << 1)]     + acc2[r][0];
    ys[r * D_ + (tid << 1) + 1] = qs[r][(tid << 1) + 1] + acc2[r][1];
  }
  __syncthreads();
  float g3a = g3[tid],  g3b = g3[tid + 256];
  float be3a = be3[tid], be3b = be3[tid + 256];
  float* rl = &qs[0][0];
  for (int r = 0; r < 8; ++r) {
    float v0 = ys[r * D_ + tid], v1 = ys[r * D_ + tid + 256];
    float s = v0 + v1, sq = v0 * v0 + v1 * v1;
    #pragma unroll
    for (int o = 32; o > 0; o >>= 1) { s += __shfl_down(s, o); sq += __shfl_down(sq, o); }
    int lane = tid & 63, wid = tid >> 6;
    if (lane == 0) { rl[wid] = s; rl[4 + wid] = sq; }
    __syncthreads();
    s = rl[0] + rl[1] + rl[2] + rl[3];
    sq = rl[4] + rl[5] + rl[6] + rl[7];
    __syncthreads();
    float mean = s * (1.0f / 512.0f);
    float var = sq * (1.0f / 512.0f) - mean * mean;
    float rstd = rsqrtf(var + 1e-5f);
    int t = row_base + row0 + r;
    int b = t / SQ, tt = t - b * SQ;
    int si = tt >> 3, l = tt & 7;
    size_t ob = (((size_t)(b * S_ + si) * D_) << 3) + l;
    out[ob + ((size_t)tid << 3)]         = (v0 - mean) * rstd * g3a + be3a;
    out[ob + ((size_t)(tid + 256) << 3)] = (v1 - mean) * rstd * g3b + be3b;
  }
}

extern "C" void kernel_launch(void* const* d_in, const int* in_sizes, int n_in,
                              void* d_out, int out_size, void* d_ws, size_t ws_size,
                              hipStream_t stream) {
  const float* lags   = (const float*)d_in[0];
  const float* gamma1 = (const float*)d_in[1];
  const float* beta1  = (const float*)d_in[2];
  const float* W1     = (const float*)d_in[3];
  const float* b1     = (const float*)d_in[4];
  const float* W2     = (const float*)d_in[5];
  const float* b2     = (const float*)d_in[6];
  const float* g3     = (const float*)d_in[7];
  const float* be3    = (const float*)d_in[8];
  float* out = (float*)d_out;

  float* ws = (float*)d_ws;
  const size_t NX  = (size_t)B_ * SQ * D_;   // 6,291,456
  const size_t NXB = (size_t)SQ * D_;        //   786,432
  const size_t NS  = (size_t)SQ * SQ;        // 2,359,296

  const size_t need_full = (3 * NX + 8 * NS) * sizeof(float);  // ~151 MB (proven available)

  if (ws_size >= need_full) {
    // ---- fast path layout (~130 MB) ----
    float* x        = ws;                                   // NX f32
    float* attn     = x + NX;                               // NX f32 (later: y)
    ushort_t* q_bf  = (ushort_t*)(attn + NX);               // NX us
    ushort_t* w1t   = q_bf + NX;                            // H*D us
    ushort_t* w2t   = w1t + (size_t)H_ * D_;                // H*D us
    ushort_t* region = w2t + (size_t)H_ * D_;               // 8*NS + 2*NX us
    ushort_t* sc_bf = region;                               // scores / P, bf16, in-place
    ushort_t* x_bf  = region + 8 * NS;
    ushort_t* xT_bf = x_bf + NX;
    ushort_t* mid_bf = region;                              // aliases dead sc/x_bf/xT_bf

    k_build_x<<<dim3((unsigned)(NX / 256)), 256, 0, stream>>>(lags, x, x_bf, 0);
    k_xt<<<dim3(SQ / 64, D_ / 64, B_), 256, 0, stream>>>(x_bf, xT_bf);
    k_wt<<<dim3(H_ / 64, D_ / 64), 256, 0, stream>>>(W1, w1t, D_, H_);
    k_wt<<<dim3(D_ / 64, H_ / 64), 256, 0, stream>>>(W2, w2t, H_, D_);
    // scores = scale * X X^T -> bf16
    k_gemm<2><<<dim3(SQ / 128, SQ / 128, B_), 256, 0, stream>>>(
        x_bf, x_bf, nullptr, sc_bf, SQ, D_, SQ, NXB, NXB, NS, SCALE_QK);
    k_softmax_bf<<<dim3(SQ, 1, B_), 256, 0, stream>>>(sc_bf);
    // attn = P @ X -> f32
    k_gemm<3><<<dim3(D_ / 128, SQ / 128, B_), 256, 0, stream>>>(
        sc_bf, xT_bf, nullptr, attn, SQ, SQ, D_, NS, NXB, NXB, 1.0f);
    k_ln1b<<<dim3(NROW), 256, 0, stream>>>(x, attn, gamma1, beta1, q_bf);
    // mid = gelu(q @ W1 + b1) -> bf16
    k_gemm<0><<<dim3(H_ / 128, NROW / 128, 1), 256, 0, stream>>>(
        q_bf, w1t, b1, mid_bf, NROW, D_, H_, 0, 0, 0, 1.0f);
    // y = mid @ W2 + b2 -> f32 (attn buffer)
    k_gemm<1><<<dim3(D_ / 128, NROW / 128, 1), 256, 0, stream>>>(
        mid_bf, w2t, b2, attn, NROW, H_, D_, 0, 0, 0, 1.0f);
    k_ln3<<<dim3(NROW), 256, 0, stream>>>(attn, q_bf, g3, be3, out);
  } else {
    // ---- minimal-footprint fallback (fp32, per-batch) ----
    float* xb   = ws;
    float* sc   = xb + NXB;
    float* atb  = sc + NS;
    float* qb   = atb + NXB;
    for (int b = 0; b < B_; ++b) {
      k_build_x<<<dim3((unsigned)(NXB / 256)), 256, 0, stream>>>(lags, xb, nullptr, b);
      k_scores<<<dim3(SQ / TS, SQ / TS, 1), 256, 0, stream>>>(xb, sc, b);
      k_softmax<<<dim3(SQ, 1, 1), 256, 0, stream>>>(sc);
      k_attn<<<dim3(D_ / TS, SQ / TS, 1), 256, 0, stream>>>(xb, sc, atb);
      k_ln1<<<dim3(SQ), 256, 0, stream>>>(xb, atb, gamma1, beta1, qb);
      k_ffn<<<dim3(SQ / 8), 256, 0, stream>>>(qb, W1, b1, W2, b2, g3, be3, out, b * SQ);
    }
  }
}

// Round 6
// 347.436 us; speedup vs baseline: 5.0448x; 1.1441x over previous
//
#include <hip/hip_runtime.h>
#include <hip/hip_bf16.h>
#include <math.h>

#define B_ 8
#define S_ 192
#define D_ 512
#define L_ 8
#define SQ 1536   // S_*L_
#define H_ 2048
#define NROW (B_*SQ)   // 12288
#define SCALE_QK 0.04419417382415922f  // 1/sqrt(512)

typedef unsigned short ushort_t;
typedef unsigned int uint_t;
typedef __attribute__((ext_vector_type(8))) short bf16x8;
typedef __attribute__((ext_vector_type(4))) float f32x4;

__device__ __forceinline__ float bfu2f(ushort_t u) { return __uint_as_float((unsigned)u << 16); }
__device__ __forceinline__ ushort_t f2bfu(float f) {
  __hip_bfloat16 h = __float2bfloat16(f);
  return *reinterpret_cast<ushort_t*>(&h);
}

// async global->LDS, 16B per lane; LDS dest = wave-uniform base + lane*16
__device__ __forceinline__ void gl_lds16(const ushort_t* g, ushort_t* l) {
  __builtin_amdgcn_global_load_lds(
      (const __attribute__((address_space(1))) unsigned int*)g,
      (__attribute__((address_space(3))) unsigned int*)l, 16, 0, 0);
}

// ---- fast build x: one block per (b,si); coalesced read of 4096 floats, LDS transpose ----
__global__ __launch_bounds__(256) void k_build_x_f(const float* __restrict__ lags,
                                                   float* __restrict__ x,
                                                   ushort_t* __restrict__ x_bf) {
  __shared__ float tile[512][9];
  const int tid = threadIdx.x;
  const float* in = lags + (size_t)blockIdx.x * 4096;
  #pragma unroll
  for (int it = 0; it < 4; ++it) {
    int f = (tid + it * 256) * 4;
    float4 v = *reinterpret_cast<const float4*>(in + f);
    int k = f >> 3, l0 = f & 7;
    tile[k][l0] = v.x; tile[k][l0 + 1] = v.y; tile[k][l0 + 2] = v.z; tile[k][l0 + 3] = v.w;
  }
  __syncthreads();
  const int l = tid >> 5, kbase = tid & 31;
  const size_t r = (size_t)blockIdx.x * 8 + l;
  #pragma unroll
  for (int j = 0; j < 16; ++j) {
    int k = kbase + 32 * j;
    float v = tile[k][l];
    x[r * D_ + k] = v;
    x_bf[r * D_ + k] = f2bfu(v);
  }
}

// ---- 64x64 LDS transpose: x_bf [SQ][D] -> xT_bf [D][SQ], per batch z ----
__global__ __launch_bounds__(256) void k_xt(const ushort_t* __restrict__ x_bf,
                                            ushort_t* __restrict__ xT) {
  __shared__ ushort_t tile[64][65];
  int t0 = blockIdx.x * 64, d0 = blockIdx.y * 64;
  const ushort_t* X = x_bf + (size_t)blockIdx.z * SQ * D_;
  ushort_t* XT = xT + (size_t)blockIdx.z * SQ * D_;
  for (int i = threadIdx.x; i < 4096; i += 256) {
    int tt = i >> 6, dd = i & 63;
    tile[dd][tt] = X[(size_t)(t0 + tt) * D_ + d0 + dd];
  }
  __syncthreads();
  for (int i = threadIdx.x; i < 4096; i += 256) {
    int dd = i >> 6, tt = i & 63;
    XT[(size_t)(d0 + dd) * SQ + t0 + tt] = tile[dd][tt];
  }
}

// ---- cast + transpose weights: W[K][N] fp32 -> Wt[N][K] bf16 ----
__global__ __launch_bounds__(256) void k_wt(const float* __restrict__ W,
                                            ushort_t* __restrict__ Wt,
                                            int K, int N) {
  __shared__ ushort_t tile[64][65];
  int n0 = blockIdx.x * 64, k0 = blockIdx.y * 64;
  for (int i = threadIdx.x; i < 4096; i += 256) {
    int kk = i >> 6, nn = i & 63;
    tile[nn][kk] = f2bfu(W[(size_t)(k0 + kk) * N + n0 + nn]);
  }
  __syncthreads();
  for (int i = threadIdx.x; i < 4096; i += 256) {
    int nn = i >> 6, kk = i & 63;
    Wt[(size_t)(n0 + nn) * K + k0 + kk] = tile[nn][kk];
  }
}

// ---- bf16 MFMA GEMM (m97-style async staging): C[M,N] = A[M,K] @ Bt[N,K]^T
// MODE 0: +bias, gelu -> bf16 | 1: +bias -> f32 | 2: *scale -> bf16 | 3: -> f32
template<int MODE>
__global__ __launch_bounds__(256) void k_gemm(const ushort_t* __restrict__ A,
                                              const ushort_t* __restrict__ Bt,
                                              const float* __restrict__ bias,
                                              void* __restrict__ Cout,
                                              int M, int K, int N,
                                              size_t sAz, size_t sBz, size_t sCz,
                                              float scale) {
  A  += (size_t)blockIdx.z * sAz;
  Bt += (size_t)blockIdx.z * sBz;
  __shared__ ushort_t As[128 * 32];   // unpadded: layout forced by global_load_lds
  __shared__ ushort_t Bs[128 * 32];
  const int tid = threadIdx.x;
  const int m0 = blockIdx.y * 128, n0 = blockIdx.x * 128;
  const int w = tid >> 6, lane = tid & 63;
  const int wr = w >> 1, wc = w & 1;
  const int l15 = lane & 15, quad = lane >> 4;
  // staging coords: wave w covers rows [w*32, w*32+32) in two 16-row chunks
  const int srow = w * 32 + (lane >> 2);   // +0 / +16
  const int scol = (lane & 3) * 8;         // ushort col
  ushort_t* lA = &As[(w * 32) * 32];       // wave-uniform LDS bases
  ushort_t* lB = &Bs[(w * 32) * 32];

  f32x4 acc[4][4];
  if (MODE <= 1) {
    #pragma unroll
    for (int nj = 0; nj < 4; ++nj) {
      float bv = bias[n0 + wc * 64 + nj * 16 + l15];
      #pragma unroll
      for (int mi = 0; mi < 4; ++mi) acc[mi][nj] = (f32x4){bv, bv, bv, bv};
    }
  } else {
    #pragma unroll
    for (int nj = 0; nj < 4; ++nj)
      #pragma unroll
      for (int mi = 0; mi < 4; ++mi) acc[mi][nj] = (f32x4){0.f, 0.f, 0.f, 0.f};
  }

  for (int k0 = 0; k0 < K; k0 += 32) {
    const ushort_t* gA = A  + (size_t)(m0 + srow) * K + k0 + scol;
    const ushort_t* gB = Bt + (size_t)(n0 + srow) * K + k0 + scol;
    __syncthreads();                       // prior iter's LDS reads done
    gl_lds16(gA, lA);
    gl_lds16(gA + (size_t)16 * K, lA + 16 * 32);
    gl_lds16(gB, lB);
    gl_lds16(gB + (size_t)16 * K, lB + 16 * 32);
    __syncthreads();                       // drains vmcnt (async loads landed)
    bf16x8 af[4], bfv[4];
    #pragma unroll
    for (int mi = 0; mi < 4; ++mi)
      af[mi] = *reinterpret_cast<const bf16x8*>(&As[(wr * 64 + mi * 16 + l15) * 32 + quad * 8]);
    #pragma unroll
    for (int nj = 0; nj < 4; ++nj)
      bfv[nj] = *reinterpret_cast<const bf16x8*>(&Bs[(wc * 64 + nj * 16 + l15) * 32 + quad * 8]);
    #pragma unroll
    for (int mi = 0; mi < 4; ++mi)
      #pragma unroll
      for (int nj = 0; nj < 4; ++nj)
        acc[mi][nj] = __builtin_amdgcn_mfma_f32_16x16x32_bf16(af[mi], bfv[nj], acc[mi][nj], 0, 0, 0);
  }

  ushort_t* Cb = (ushort_t*)Cout + (size_t)blockIdx.z * sCz;
  float*    Cf = (float*)Cout    + (size_t)blockIdx.z * sCz;
  #pragma unroll
  for (int mi = 0; mi < 4; ++mi)
    #pragma unroll
    for (int nj = 0; nj < 4; ++nj) {
      int gc = n0 + wc * 64 + nj * 16 + l15;
      #pragma unroll
      for (int r = 0; r < 4; ++r) {
        int gr = m0 + wr * 64 + mi * 16 + quad * 4 + r;
        float v = acc[mi][nj][r];
        if (MODE == 0) {
          v = 0.5f * v * (1.0f + erff(v * 0.70710678118654752f));
          Cb[(size_t)gr * N + gc] = f2bfu(v);
        } else if (MODE == 1) {
          Cf[(size_t)gr * N + gc] = v;
        } else if (MODE == 2) {
          Cb[(size_t)gr * N + gc] = f2bfu(v * scale);
        } else {
          Cf[(size_t)gr * N + gc] = v;
        }
      }
    }
}

// ---- softmax rows in place, bf16 storage (uint-packed), fp32 math ----
__global__ __launch_bounds__(256) void k_softmax_bf(ushort_t* __restrict__ sc) {
  uint_t* row = (uint_t*)(sc + (size_t)blockIdx.z * SQ * SQ + (size_t)blockIdx.x * SQ);
  int tid = threadIdx.x;
  __shared__ float red[8];
  float v[6];
  float m = -1e30f;
  #pragma unroll
  for (int k = 0; k < 3; ++k) {
    uint_t u = row[tid + k * 256];
    v[2*k]   = __uint_as_float(u << 16);
    v[2*k+1] = __uint_as_float(u & 0xffff0000u);
    m = fmaxf(m, fmaxf(v[2*k], v[2*k+1]));
  }
  #pragma unroll
  for (int o = 32; o > 0; o >>= 1) m = fmaxf(m, __shfl_down(m, o));
  if ((tid & 63) == 0) red[tid >> 6] = m;
  __syncthreads();
  m = fmaxf(fmaxf(red[0], red[1]), fmaxf(red[2], red[3]));
  __syncthreads();
  float ssum = 0.f;
  #pragma unroll
  for (int k = 0; k < 6; ++k) { v[k] = expf(v[k] - m); ssum += v[k]; }
  #pragma unroll
  for (int o = 32; o > 0; o >>= 1) ssum += __shfl_down(ssum, o);
  if ((tid & 63) == 0) red[4 + (tid >> 6)] = ssum;
  __syncthreads();
  float inv = 1.0f / (red[4] + red[5] + red[6] + red[7]);
  #pragma unroll
  for (int k = 0; k < 3; ++k) {
    uint_t lo = f2bfu(v[2*k] * inv);
    uint_t hi = f2bfu(v[2*k+1] * inv);
    row[tid + k * 256] = (hi << 16) | lo;
  }
}

// ---- LN1 -> bf16 q ----
__global__ __launch_bounds__(256) void k_ln1b(const float* __restrict__ x,
                                              const float* __restrict__ attn,
                                              const float* __restrict__ g,
                                              const float* __restrict__ be,
                                              ushort_t* __restrict__ qbf) {
  size_t base = (size_t)blockIdx.x * D_;
  int tid = threadIdx.x;
  __shared__ float rl[8];
  float v0 = x[base + tid] + attn[base + tid];
  float v1 = x[base + tid + 256] + attn[base + tid + 256];
  float s = v0 + v1, sq = v0 * v0 + v1 * v1;
  #pragma unroll
  for (int o = 32; o > 0; o >>= 1) { s += __shfl_down(s, o); sq += __shfl_down(sq, o); }
  int lane = tid & 63, wid = tid >> 6;
  if (lane == 0) { rl[wid] = s; rl[4 + wid] = sq; }
  __syncthreads();
  s = rl[0] + rl[1] + rl[2] + rl[3];
  sq = rl[4] + rl[5] + rl[6] + rl[7];
  float mean = s * (1.0f / 512.0f);
  float var = sq * (1.0f / 512.0f) - mean * mean;
  float rstd = rsqrtf(var + 1e-5f);
  qbf[base + tid]       = f2bfu((v0 - mean) * rstd * g[tid] + be[tid]);
  qbf[base + tid + 256] = f2bfu((v1 - mean) * rstd * g[tid + 256] + be[tid + 256]);
}

// ---- fast LN3: one block per (b,si); LDS transpose -> fully coalesced output ----
__global__ __launch_bounds__(256) void k_ln3_f(const float* __restrict__ y,
                                               const ushort_t* __restrict__ qbf,
                                               const float* __restrict__ g3,
                                               const float* __restrict__ be3,
                                               float* __restrict__ out) {
  __shared__ float ynorm[8][512];
  const int tid = threadIdx.x;
  const int w = tid >> 6, lane = tid & 63;
  // wave w handles rows l = 2w, 2w+1
  #pragma unroll
  for (int rr = 0; rr < 2; ++rr) {
    int l = 2 * w + rr;
    size_t t = (size_t)blockIdx.x * 8 + l;
    float v[8];
    float s = 0.f, sq = 0.f;
    #pragma unroll
    for (int j = 0; j < 8; ++j) {
      int k = lane + 64 * j;
      v[j] = y[t * D_ + k] + bfu2f(qbf[t * D_ + k]);
      s += v[j]; sq += v[j] * v[j];
    }
    #pragma unroll
    for (int o = 32; o > 0; o >>= 1) { s += __shfl_down(s, o); sq += __shfl_down(sq, o); }
    s = __shfl(s, 0); sq = __shfl(sq, 0);
    float mean = s * (1.0f / 512.0f);
    float var = sq * (1.0f / 512.0f) - mean * mean;
    float rstd = rsqrtf(var + 1e-5f);
    #pragma unroll
    for (int j = 0; j < 8; ++j) {
      int k = lane + 64 * j;
      ynorm[l][k] = (v[j] - mean) * rstd * g3[k] + be3[k];
    }
  }
  __syncthreads();
  // write out[(b*192+si)*512 + k][l] for l=0..7: 32B contiguous per k
  float* ob = out + (size_t)blockIdx.x * 4096;
  #pragma unroll
  for (int kk = 0; kk < 2; ++kk) {
    int k = tid * 2 + kk;
    float4 lo = make_float4(ynorm[0][k], ynorm[1][k], ynorm[2][k], ynorm[3][k]);
    float4 hi = make_float4(ynorm[4][k], ynorm[5][k], ynorm[6][k], ynorm[7][k]);
    *reinterpret_cast<float4*>(ob + (size_t)k * 8)     = lo;
    *reinterpret_cast<float4*>(ob + (size_t)k * 8 + 4) = hi;
  }
}

// ================= slow-path fp32 kernels (fallback only) =================
#define TS 64
#define KT 16
__global__ __launch_bounds__(256) void k_build_x_s(const float* __restrict__ lags,
                                                   float* __restrict__ x, int b_base) {
  int idx = blockIdx.x * 256 + threadIdx.x;
  int k = idx & (D_ - 1);
  int r = idx >> 9;
  int b = b_base + r / SQ;
  int t = r - (r / SQ) * SQ;
  int si = t >> 3, l = t & 7;
  size_t src = (((size_t)(b * S_ + si) * D_ + k) << 3) + l;
  x[idx] = lags[src];
}

__global__ __launch_bounds__(256) void k_scores(const float* __restrict__ x,
                                                float* __restrict__ sc, int b_base) {
  const float* A = x;
  float* C = sc;
  __shared__ float As[TS][KT + 1];
  __shared__ float Bs[TS][KT + 1];
  int tx = threadIdx.x & 15, ty = threadIdx.x >> 4;
  int j0 = blockIdx.x * TS, i0 = blockIdx.y * TS;
  float acc[4][4] = {};
  int lk = threadIdx.x & 15, lr = threadIdx.x >> 4;
  for (int k0 = 0; k0 < D_; k0 += KT) {
    #pragma unroll
    for (int it = 0; it < 4; ++it) {
      As[lr + 16 * it][lk] = A[(size_t)(i0 + lr + 16 * it) * D_ + k0 + lk];
      Bs[lr + 16 * it][lk] = A[(size_t)(j0 + lr + 16 * it) * D_ + k0 + lk];
    }
    __syncthreads();
    #pragma unroll
    for (int kk = 0; kk < KT; ++kk) {
      float a[4], bb[4];
      #pragma unroll
      for (int r = 0; r < 4; ++r) a[r] = As[ty * 4 + r][kk];
      #pragma unroll
      for (int c = 0; c < 4; ++c) bb[c] = Bs[tx * 4 + c][kk];
      #pragma unroll
      for (int r = 0; r < 4; ++r)
        #pragma unroll
        for (int c = 0; c < 4; ++c) acc[r][c] = fmaf(a[r], bb[c], acc[r][c]);
    }
    __syncthreads();
  }
  #pragma unroll
  for (int r = 0; r < 4; ++r) {
    float4 v = make_float4(acc[r][0]*SCALE_QK, acc[r][1]*SCALE_QK,
                           acc[r][2]*SCALE_QK, acc[r][3]*SCALE_QK);
    *reinterpret_cast<float4*>(&C[(size_t)(i0 + ty*4 + r) * SQ + j0 + tx*4]) = v;
  }
}

__global__ __launch_bounds__(256) void k_softmax(float* __restrict__ sc) {
  float* row = sc + (size_t)blockIdx.x * SQ;
  int tid = threadIdx.x;
  __shared__ float red[8];
  float m = -1e30f;
  for (int j = tid; j < SQ; j += 256) m = fmaxf(m, row[j]);
  #pragma unroll
  for (int o = 32; o > 0; o >>= 1) m = fmaxf(m, __shfl_down(m, o));
  if ((tid & 63) == 0) red[tid >> 6] = m;
  __syncthreads();
  m = fmaxf(fmaxf(red[0], red[1]), fmaxf(red[2], red[3]));
  __syncthreads();
  float ssum = 0.f;
  for (int j = tid; j < SQ; j += 256) { float e = expf(row[j] - m); row[j] = e; ssum += e; }
  #pragma unroll
  for (int o = 32; o > 0; o >>= 1) ssum += __shfl_down(ssum, o);
  if ((tid & 63) == 0) red[4 + (tid >> 6)] = ssum;
  __syncthreads();
  float inv = 1.0f / (red[4] + red[5] + red[6] + red[7]);
  for (int j = tid; j < SQ; j += 256) row[j] *= inv;
}

__global__ __launch_bounds__(256) void k_attn(const float* __restrict__ x,
                                              const float* __restrict__ sc,
                                              float* __restrict__ attn) {
  const float* X = x;
  const float* P = sc;
  float* O = attn;
  __shared__ float Ps[TS][KT + 1];
  __shared__ float Xs[KT][TS];
  int tx = threadIdx.x & 15, ty = threadIdx.x >> 4;
  int j0 = blockIdx.x * TS, i0 = blockIdx.y * TS;
  float acc[4][4] = {};
  int lk = threadIdx.x & 15, lr = threadIdx.x >> 4;
  int lc = threadIdx.x & 63, lrow = threadIdx.x >> 6;
  for (int k0 = 0; k0 < SQ; k0 += KT) {
    #pragma unroll
    for (int it = 0; it < 4; ++it)
      Ps[lr + 16 * it][lk] = P[(size_t)(i0 + lr + 16 * it) * SQ + k0 + lk];
    #pragma unroll
    for (int it = 0; it < 4; ++it)
      Xs[lrow + 4 * it][lc] = X[(size_t)(k0 + lrow + 4 * it) * D_ + j0 + lc];
    __syncthreads();
    #pragma unroll
    for (int kk = 0; kk < KT; ++kk) {
      float a[4], bb[4];
      #pragma unroll
      for (int r = 0; r < 4; ++r) a[r] = Ps[ty * 4 + r][kk];
      #pragma unroll
      for (int c = 0; c < 4; ++c) bb[c] = Xs[kk][tx * 4 + c];
      #pragma unroll
      for (int r = 0; r < 4; ++r)
        #pragma unroll
        for (int c = 0; c < 4; ++c) acc[r][c] = fmaf(a[r], bb[c], acc[r][c]);
    }
    __syncthreads();
  }
  #pragma unroll
  for (int r = 0; r < 4; ++r) {
    float4 v = make_float4(acc[r][0], acc[r][1], acc[r][2], acc[r][3]);
    *reinterpret_cast<float4*>(&O[(size_t)(i0 + ty*4 + r) * D_ + j0 + tx*4]) = v;
  }
}

__global__ __launch_bounds__(256) void k_ln1(const float* __restrict__ x,
                                             const float* __restrict__ attn,
                                             const float* __restrict__ g,
                                             const float* __restrict__ be,
                                             float* __restrict__ qout) {
  size_t base = (size_t)blockIdx.x * D_;
  int tid = threadIdx.x;
  __shared__ float rl[8];
  float v0 = x[base + tid] + attn[base + tid];
  float v1 = x[base + tid + 256] + attn[base + tid + 256];
  float s = v0 + v1, sq = v0 * v0 + v1 * v1;
  #pragma unroll
  for (int o = 32; o > 0; o >>= 1) { s += __shfl_down(s, o); sq += __shfl_down(sq, o); }
  int lane = tid & 63, wid = tid >> 6;
  if (lane == 0) { rl[wid] = s; rl[4 + wid] = sq; }
  __syncthreads();
  s = rl[0] + rl[1] + rl[2] + rl[3];
  sq = rl[4] + rl[5] + rl[6] + rl[7];
  float mean = s * (1.0f / 512.0f);
  float var = sq * (1.0f / 512.0f) - mean * mean;
  float rstd = rsqrtf(var + 1e-5f);
  qout[base + tid]       = (v0 - mean) * rstd * g[tid] + be[tid];
  qout[base + tid + 256] = (v1 - mean) * rstd * g[tid + 256] + be[tid + 256];
}

__global__ __launch_bounds__(256, 2) void k_ffn(
    const float* __restrict__ q,
    const float* __restrict__ W1, const float* __restrict__ b1,
    const float* __restrict__ W2, const float* __restrict__ b2,
    const float* __restrict__ g3, const float* __restrict__ be3,
    float* __restrict__ out, int row_base)
{
  __shared__ float qs[8][D_];
  __shared__ float mid[8][H_];
  const int tid = threadIdx.x;
  const int row0 = blockIdx.x * 8;
  for (int idx = tid; idx < 8 * D_; idx += 256)
    qs[idx >> 9][idx & (D_ - 1)] = q[(size_t)row0 * D_ + idx];
  __syncthreads();
  float acc[8][8];
  {
    float4 bA = *reinterpret_cast<const float4*>(b1 + (tid << 3));
    float4 bB = *reinterpret_cast<const float4*>(b1 + (tid << 3) + 4);
    float bv[8] = {bA.x, bA.y, bA.z, bA.w, bB.x, bB.y, bB.z, bB.w};
    #pragma unroll
    for (int jj = 0; jj < 8; ++jj)
      #pragma unroll
      for (int r = 0; r < 8; ++r) acc[jj][r] = bv[jj];
  }
  for (int k4 = 0; k4 < D_ / 4; ++k4) {
    float4 qv[8];
    #pragma unroll
    for (int r = 0; r < 8; ++r)
      qv[r] = *reinterpret_cast<const float4*>(&qs[r][k4 << 2]);
    #pragma unroll
    for (int kk = 0; kk < 4; ++kk) {
      const int k = (k4 << 2) + kk;
      float4 wA = *reinterpret_cast<const float4*>(W1 + (size_t)k * H_ + (tid << 3));
      float4 wB = *reinterpret_cast<const float4*>(W1 + (size_t)k * H_ + (tid << 3) + 4);
      float wv[8] = {wA.x, wA.y, wA.z, wA.w, wB.x, wB.y, wB.z, wB.w};
      #pragma unroll
      for (int r = 0; r < 8; ++r) {
        float qk = (kk == 0) ? qv[r].x : (kk == 1) ? qv[r].y : (kk == 2) ? qv[r].z : qv[r].w;
        #pragma unroll
        for (int jj = 0; jj < 8; ++jj) acc[jj][r] = fmaf(qk, wv[jj], acc[jj][r]);
      }
    }
  }
  #pragma unroll
  for (int jj = 0; jj < 8; ++jj)
    #pragma unroll
    for (int r = 0; r < 8; ++r) {
      float v = acc[jj][r];
      mid[r][(tid << 3) + jj] = 0.5f * v * (1.0f + erff(v * 0.70710678118654752f));
    }
  __syncthreads();
  float acc2[8][2];
  {
    float b20 = b2[tid << 1], b21 = b2[(tid << 1) + 1];
    #pragma unroll
    for (int r = 0; r < 8; ++r) { acc2[r][0] = b20; acc2[r][1] = b21; }
  }
  for (int j4 = 0; j4 < H_ / 4; ++j4) {
    float4 mv[8];
    #pragma unroll
    for (int r = 0; r < 8; ++r)
      mv[r] = *reinterpret_cast<const float4*>(&mid[r][j4 << 2]);
    #pragma unroll
    for (int kk = 0; kk < 4; ++kk) {
      const int j = (j4 << 2) + kk;
      float2 wv = *reinterpret_cast<const float2*>(W2 + (size_t)j * D_ + (tid << 1));
      #pragma unroll
      for (int r = 0; r < 8; ++r) {
        float m = (kk == 0) ? mv[r].x : (kk == 1) ? mv[r].y : (kk == 2) ? mv[r].z : mv[r].w;
        acc2[r][0] = fmaf(m, wv.x, acc2[r][0]);
        acc2[r][1] = fmaf(m, wv.y, acc2[r][1]);
      }
    }
  }
  __syncthreads();
  float* ys = &mid[0][0];
  #pragma unroll
  for (int r = 0; r < 8; ++r) {
    ys[r * D_ + (tid << 1)]     = qs[r][(tid << 1)]     + acc2[r][0];
    ys[r * D_ + (tid << 1) + 1] = qs[r][(tid << 1) + 1] + acc2[r][1];
  }
  __syncthreads();
  float g3a = g3[tid],  g3b = g3[tid + 256];
  float be3a = be3[tid], be3b = be3[tid + 256];
  float* rl = &qs[0][0];
  for (int r = 0; r < 8; ++r) {
    float v0 = ys[r * D_ + tid], v1 = ys[r * D_ + tid + 256];
    float s = v0 + v1, sq = v0 * v0 + v1 * v1;
    #pragma unroll
    for (int o = 32; o > 0; o >>= 1) { s += __shfl_down(s, o); sq += __shfl_down(sq, o); }
    int lane = tid & 63, wid = tid >> 6;
    if (lane == 0) { rl[wid] = s; rl[4 + wid] = sq; }
    __syncthreads();
    s = rl[0] + rl[1] + rl[2] + rl[3];
    sq = rl[4] + rl[5] + rl[6] + rl[7];
    __syncthreads();
    float mean = s * (1.0f / 512.0f);
    float var = sq * (1.0f / 512.0f) - mean * mean;
    float rstd = rsqrtf(var + 1e-5f);
    int t = row_base + row0 + r;
    int b = t / SQ, tt = t - b * SQ;
    int si = tt >> 3, l = tt & 7;
    size_t ob = (((size_t)(b * S_ + si) * D_) << 3) + l;
    out[ob + ((size_t)tid << 3)]         = (v0 - mean) * rstd * g3a + be3a;
    out[ob + ((size_t)(tid + 256) << 3)] = (v1 - mean) * rstd * g3b + be3b;
  }
}

extern "C" void kernel_launch(void* const* d_in, const int* in_sizes, int n_in,
                              void* d_out, int out_size, void* d_ws, size_t ws_size,
                              hipStream_t stream) {
  const float* lags   = (const float*)d_in[0];
  const float* gamma1 = (const float*)d_in[1];
  const float* beta1  = (const float*)d_in[2];
  const float* W1     = (const float*)d_in[3];
  const float* b1     = (const float*)d_in[4];
  const float* W2     = (const float*)d_in[5];
  const float* b2     = (const float*)d_in[6];
  const float* g3     = (const float*)d_in[7];
  const float* be3    = (const float*)d_in[8];
  float* out = (float*)d_out;

  float* ws = (float*)d_ws;
  const size_t NX  = (size_t)B_ * SQ * D_;   // 6,291,456
  const size_t NXB = (size_t)SQ * D_;        //   786,432
  const size_t NS  = (size_t)SQ * SQ;        // 2,359,296

  const size_t need_full = (3 * NX + 8 * NS) * sizeof(float);  // ~151 MB (proven available)

  if (ws_size >= need_full) {
    // ---- fast path layout (~130 MB) ----
    float* x        = ws;                                   // NX f32
    float* attn     = x + NX;                               // NX f32 (later: y)
    ushort_t* q_bf  = (ushort_t*)(attn + NX);               // NX us
    ushort_t* w1t   = q_bf + NX;                            // H*D us
    ushort_t* w2t   = w1t + (size_t)H_ * D_;                // H*D us
    ushort_t* region = w2t + (size_t)H_ * D_;               // 8*NS + 2*NX us
    ushort_t* sc_bf = region;                               // scores / P, bf16, in-place
    ushort_t* x_bf  = region + 8 * NS;
    ushort_t* xT_bf = x_bf + NX;
    ushort_t* mid_bf = region;                              // aliases dead sc/x_bf/xT_bf

    k_build_x_f<<<dim3(B_ * S_), 256, 0, stream>>>(lags, x, x_bf);
    k_xt<<<dim3(SQ / 64, D_ / 64, B_), 256, 0, stream>>>(x_bf, xT_bf);
    k_wt<<<dim3(H_ / 64, D_ / 64), 256, 0, stream>>>(W1, w1t, D_, H_);
    k_wt<<<dim3(D_ / 64, H_ / 64), 256, 0, stream>>>(W2, w2t, H_, D_);
    // scores = scale * X X^T -> bf16
    k_gemm<2><<<dim3(SQ / 128, SQ / 128, B_), 256, 0, stream>>>(
        x_bf, x_bf, nullptr, sc_bf, SQ, D_, SQ, NXB, NXB, NS, SCALE_QK);
    k_softmax_bf<<<dim3(SQ, 1, B_), 256, 0, stream>>>(sc_bf);
    // attn = P @ X -> f32
    k_gemm<3><<<dim3(D_ / 128, SQ / 128, B_), 256, 0, stream>>>(
        sc_bf, xT_bf, nullptr, attn, SQ, SQ, D_, NS, NXB, NXB, 1.0f);
    k_ln1b<<<dim3(NROW), 256, 0, stream>>>(x, attn, gamma1, beta1, q_bf);
    // mid = gelu(q @ W1 + b1) -> bf16
    k_gemm<0><<<dim3(H_ / 128, NROW / 128, 1), 256, 0, stream>>>(
        q_bf, w1t, b1, mid_bf, NROW, D_, H_, 0, 0, 0, 1.0f);
    // y = mid @ W2 + b2 -> f32 (attn buffer)
    k_gemm<1><<<dim3(D_ / 128, NROW / 128, 1), 256, 0, stream>>>(
        mid_bf, w2t, b2, attn, NROW, H_, D_, 0, 0, 0, 1.0f);
    k_ln3_f<<<dim3(B_ * S_), 256, 0, stream>>>(attn, q_bf, g3, be3, out);
  } else {
    // ---- minimal-footprint fallback (fp32, per-batch) ----
    float* xb   = ws;
    float* sc   = xb + NXB;
    float* atb  = sc + NS;
    float* qb   = atb + NXB;
    for (int b = 0; b < B_; ++b) {
      k_build_x_s<<<dim3((unsigned)(NXB / 256)), 256, 0, stream>>>(lags, xb, b);
      k_scores<<<dim3(SQ / TS, SQ / TS, 1), 256, 0, stream>>>(xb, sc, b);
      k_softmax<<<dim3(SQ, 1, 1), 256, 0, stream>>>(sc);
      k_attn<<<dim3(D_ / TS, SQ / TS, 1), 256, 0, stream>>>(xb, sc, atb);
      k_ln1<<<dim3(SQ), 256, 0, stream>>>(xb, atb, gamma1, beta1, qb);
      k_ffn<<<dim3(SQ / 8), 256, 0, stream>>>(qb, W1, b1, W2, b2, g3, be3, out, b * SQ);
    }
  }
}

// Round 7
// 306.081 us; speedup vs baseline: 5.7264x; 1.1351x over previous
//
#include <hip/hip_runtime.h>
#include <hip/hip_bf16.h>
#include <math.h>

#define B_ 8
#define S_ 192
#define D_ 512
#define L_ 8
#define SQ 1536   // S_*L_
#define H_ 2048
#define NROW (B_*SQ)   // 12288
#define SCALE_QK 0.04419417382415922f  // 1/sqrt(512)

typedef unsigned short ushort_t;
typedef unsigned int uint_t;
typedef __attribute__((ext_vector_type(8))) short bf16x8;
typedef __attribute__((ext_vector_type(4))) float f32x4;

__device__ __forceinline__ float bfu2f(ushort_t u) { return __uint_as_float((unsigned)u << 16); }
__device__ __forceinline__ ushort_t f2bfu(float f) {
  __hip_bfloat16 h = __float2bfloat16(f);
  return *reinterpret_cast<ushort_t*>(&h);
}

// exact-erf GELU via Abramowitz-Stegun 7.1.26 (|erf err| < 1.5e-7), ~12 VALU ops
__device__ __forceinline__ float gelu_fast(float x) {
  float z = fabsf(x) * 0.70710678118654752f;
  float t = __builtin_amdgcn_rcpf(fmaf(0.3275911f, z, 1.0f));
  float p = fmaf(1.061405429f, t, -1.453152027f);
  p = fmaf(p, t, 1.421413741f);
  p = fmaf(p, t, -0.284496736f);
  p = fmaf(p, t, 0.254829592f);
  p = p * t;
  float e = __expf(-z * z);
  float erfz = fmaf(-p, e, 1.0f);
  float s = (x >= 0.0f) ? erfz : -erfz;
  return 0.5f * x * (1.0f + s);
}

// async global->LDS, 16B per lane; LDS dest = wave-uniform base + lane*16
__device__ __forceinline__ void gl_lds16(const ushort_t* g, ushort_t* l) {
  __builtin_amdgcn_global_load_lds(
      (const __attribute__((address_space(1))) unsigned int*)g,
      (__attribute__((address_space(3))) unsigned int*)l, 16, 0, 0);
}

// ---- fast build x: one block per (b,si); coalesced read of 4096 floats, LDS transpose ----
__global__ __launch_bounds__(256) void k_build_x_f(const float* __restrict__ lags,
                                                   float* __restrict__ x,
                                                   ushort_t* __restrict__ x_bf) {
  __shared__ float tile[512][9];
  const int tid = threadIdx.x;
  const float* in = lags + (size_t)blockIdx.x * 4096;
  #pragma unroll
  for (int it = 0; it < 4; ++it) {
    int f = (tid + it * 256) * 4;
    float4 v = *reinterpret_cast<const float4*>(in + f);
    int k = f >> 3, l0 = f & 7;
    tile[k][l0] = v.x; tile[k][l0 + 1] = v.y; tile[k][l0 + 2] = v.z; tile[k][l0 + 3] = v.w;
  }
  __syncthreads();
  const int l = tid >> 5, kbase = tid & 31;
  const size_t r = (size_t)blockIdx.x * 8 + l;
  #pragma unroll
  for (int j = 0; j < 16; ++j) {
    int k = kbase + 32 * j;
    float v = tile[k][l];
    x[r * D_ + k] = v;
    x_bf[r * D_ + k] = f2bfu(v);
  }
}

// ---- 64x64 LDS transpose: x_bf [SQ][D] -> xT_bf [D][SQ], per batch z ----
__global__ __launch_bounds__(256) void k_xt(const ushort_t* __restrict__ x_bf,
                                            ushort_t* __restrict__ xT) {
  __shared__ ushort_t tile[64][65];
  int t0 = blockIdx.x * 64, d0 = blockIdx.y * 64;
  const ushort_t* X = x_bf + (size_t)blockIdx.z * SQ * D_;
  ushort_t* XT = xT + (size_t)blockIdx.z * SQ * D_;
  for (int i = threadIdx.x; i < 4096; i += 256) {
    int tt = i >> 6, dd = i & 63;
    tile[dd][tt] = X[(size_t)(t0 + tt) * D_ + d0 + dd];
  }
  __syncthreads();
  for (int i = threadIdx.x; i < 4096; i += 256) {
    int dd = i >> 6, tt = i & 63;
    XT[(size_t)(d0 + dd) * SQ + t0 + tt] = tile[dd][tt];
  }
}

// ---- cast + transpose weights: W[K][N] fp32 -> Wt[N][K] bf16 ----
__global__ __launch_bounds__(256) void k_wt(const float* __restrict__ W,
                                            ushort_t* __restrict__ Wt,
                                            int K, int N) {
  __shared__ ushort_t tile[64][65];
  int n0 = blockIdx.x * 64, k0 = blockIdx.y * 64;
  for (int i = threadIdx.x; i < 4096; i += 256) {
    int kk = i >> 6, nn = i & 63;
    tile[nn][kk] = f2bfu(W[(size_t)(k0 + kk) * N + n0 + nn]);
  }
  __syncthreads();
  for (int i = threadIdx.x; i < 4096; i += 256) {
    int nn = i >> 6, kk = i & 63;
    Wt[(size_t)(n0 + nn) * K + k0 + kk] = tile[nn][kk];
  }
}

// ---- bf16 MFMA GEMM, BK=64 async swizzled staging: C[M,N] = A[M,K] @ Bt[N,K]^T
// MODE 0: +bias, gelu -> bf16 | 1: +bias -> f32 | 2: *scale -> bf16 | 3: -> f32
// LDS layout: row r (128 rows, 64-ushort stride); chunk c_lds stores global chunk c_lds ^ (r&7).
template<int MODE>
__global__ __launch_bounds__(256) void k_gemm(const ushort_t* __restrict__ A,
                                              const ushort_t* __restrict__ Bt,
                                              const float* __restrict__ bias,
                                              void* __restrict__ Cout,
                                              int M, int K, int N,
                                              size_t sAz, size_t sBz, size_t sCz,
                                              float scale) {
  A  += (size_t)blockIdx.z * sAz;
  Bt += (size_t)blockIdx.z * sBz;
  __shared__ ushort_t As[128 * 64];   // 16 KB
  __shared__ ushort_t Bs[128 * 64];   // 16 KB
  const int tid = threadIdx.x;
  const int m0 = blockIdx.y * 128, n0 = blockIdx.x * 128;
  const int w = tid >> 6, lane = tid & 63;
  const int wr = w >> 1, wc = w & 1;
  const int l15 = lane & 15, quad = lane >> 4;
  const int lrow8 = lane >> 3;                    // 0..7: staging row within 8-row group
  const int cg = ((lane & 7) ^ lrow8) * 8;        // swizzled global source chunk (ushorts)
  const int xsw = l15 & 7;                        // fragment-read xor
  ushort_t* lA = &As[(w * 32) * 64];              // wave-uniform LDS bases
  ushort_t* lB = &Bs[(w * 32) * 64];

  f32x4 acc[4][4];
  if (MODE <= 1) {
    #pragma unroll
    for (int nj = 0; nj < 4; ++nj) {
      float bv = bias[n0 + wc * 64 + nj * 16 + l15];
      #pragma unroll
      for (int mi = 0; mi < 4; ++mi) acc[mi][nj] = (f32x4){bv, bv, bv, bv};
    }
  } else {
    #pragma unroll
    for (int nj = 0; nj < 4; ++nj)
      #pragma unroll
      for (int mi = 0; mi < 4; ++mi) acc[mi][nj] = (f32x4){0.f, 0.f, 0.f, 0.f};
  }

  for (int k0 = 0; k0 < K; k0 += 64) {
    const ushort_t* gA = A  + (size_t)(m0 + w * 32 + lrow8) * K + k0 + cg;
    const ushort_t* gB = Bt + (size_t)(n0 + w * 32 + lrow8) * K + k0 + cg;
    __syncthreads();                       // prior iter's LDS reads done
    #pragma unroll
    for (int j = 0; j < 4; ++j) {
      gl_lds16(gA + (size_t)(j * 8) * K, lA + j * 8 * 64);
      gl_lds16(gB + (size_t)(j * 8) * K, lB + j * 8 * 64);
    }
    __syncthreads();                       // drains vmcnt (async loads landed)
    #pragma unroll
    for (int kk = 0; kk < 2; ++kk) {
      const int csel = ((kk * 4 + quad) ^ xsw) * 8;
      bf16x8 af[4], bfv[4];
      #pragma unroll
      for (int mi = 0; mi < 4; ++mi)
        af[mi] = *reinterpret_cast<const bf16x8*>(&As[(wr * 64 + mi * 16 + l15) * 64 + csel]);
      #pragma unroll
      for (int nj = 0; nj < 4; ++nj)
        bfv[nj] = *reinterpret_cast<const bf16x8*>(&Bs[(wc * 64 + nj * 16 + l15) * 64 + csel]);
      #pragma unroll
      for (int mi = 0; mi < 4; ++mi)
        #pragma unroll
        for (int nj = 0; nj < 4; ++nj)
          acc[mi][nj] = __builtin_amdgcn_mfma_f32_16x16x32_bf16(af[mi], bfv[nj], acc[mi][nj], 0, 0, 0);
    }
  }

  ushort_t* Cb = (ushort_t*)Cout + (size_t)blockIdx.z * sCz;
  float*    Cf = (float*)Cout    + (size_t)blockIdx.z * sCz;
  #pragma unroll
  for (int mi = 0; mi < 4; ++mi)
    #pragma unroll
    for (int nj = 0; nj < 4; ++nj) {
      int gc = n0 + wc * 64 + nj * 16 + l15;
      #pragma unroll
      for (int r = 0; r < 4; ++r) {
        int gr = m0 + wr * 64 + mi * 16 + quad * 4 + r;
        float v = acc[mi][nj][r];
        if (MODE == 0) {
          Cb[(size_t)gr * N + gc] = f2bfu(gelu_fast(v));
        } else if (MODE == 1) {
          Cf[(size_t)gr * N + gc] = v;
        } else if (MODE == 2) {
          Cb[(size_t)gr * N + gc] = f2bfu(v * scale);
        } else {
          Cf[(size_t)gr * N + gc] = v;
        }
      }
    }
}

// ---- softmax rows in place, bf16 storage (uint-packed), fp32 math ----
__global__ __launch_bounds__(256) void k_softmax_bf(ushort_t* __restrict__ sc) {
  uint_t* row = (uint_t*)(sc + (size_t)blockIdx.z * SQ * SQ + (size_t)blockIdx.x * SQ);
  int tid = threadIdx.x;
  __shared__ float red[8];
  float v[6];
  float m = -1e30f;
  #pragma unroll
  for (int k = 0; k < 3; ++k) {
    uint_t u = row[tid + k * 256];
    v[2*k]   = __uint_as_float(u << 16);
    v[2*k+1] = __uint_as_float(u & 0xffff0000u);
    m = fmaxf(m, fmaxf(v[2*k], v[2*k+1]));
  }
  #pragma unroll
  for (int o = 32; o > 0; o >>= 1) m = fmaxf(m, __shfl_down(m, o));
  if ((tid & 63) == 0) red[tid >> 6] = m;
  __syncthreads();
  m = fmaxf(fmaxf(red[0], red[1]), fmaxf(red[2], red[3]));
  __syncthreads();
  float ssum = 0.f;
  #pragma unroll
  for (int k = 0; k < 6; ++k) { v[k] = expf(v[k] - m); ssum += v[k]; }
  #pragma unroll
  for (int o = 32; o > 0; o >>= 1) ssum += __shfl_down(ssum, o);
  if ((tid & 63) == 0) red[4 + (tid >> 6)] = ssum;
  __syncthreads();
  float inv = 1.0f / (red[4] + red[5] + red[6] + red[7]);
  #pragma unroll
  for (int k = 0; k < 3; ++k) {
    uint_t lo = f2bfu(v[2*k] * inv);
    uint_t hi = f2bfu(v[2*k+1] * inv);
    row[tid + k * 256] = (hi << 16) | lo;
  }
}

// ---- LN1 -> bf16 q ----
__global__ __launch_bounds__(256) void k_ln1b(const float* __restrict__ x,
                                              const float* __restrict__ attn,
                                              const float* __restrict__ g,
                                              const float* __restrict__ be,
                                              ushort_t* __restrict__ qbf) {
  size_t base = (size_t)blockIdx.x * D_;
  int tid = threadIdx.x;
  __shared__ float rl[8];
  float v0 = x[base + tid] + attn[base + tid];
  float v1 = x[base + tid + 256] + attn[base + tid + 256];
  float s = v0 + v1, sq = v0 * v0 + v1 * v1;
  #pragma unroll
  for (int o = 32; o > 0; o >>= 1) { s += __shfl_down(s, o); sq += __shfl_down(sq, o); }
  int lane = tid & 63, wid = tid >> 6;
  if (lane == 0) { rl[wid] = s; rl[4 + wid] = sq; }
  __syncthreads();
  s = rl[0] + rl[1] + rl[2] + rl[3];
  sq = rl[4] + rl[5] + rl[6] + rl[7];
  float mean = s * (1.0f / 512.0f);
  float var = sq * (1.0f / 512.0f) - mean * mean;
  float rstd = rsqrtf(var + 1e-5f);
  qbf[base + tid]       = f2bfu((v0 - mean) * rstd * g[tid] + be[tid]);
  qbf[base + tid + 256] = f2bfu((v1 - mean) * rstd * g[tid + 256] + be[tid + 256]);
}

// ---- fast LN3: one block per (b,si); LDS transpose -> fully coalesced output ----
__global__ __launch_bounds__(256) void k_ln3_f(const float* __restrict__ y,
                                               const ushort_t* __restrict__ qbf,
                                               const float* __restrict__ g3,
                                               const float* __restrict__ be3,
                                               float* __restrict__ out) {
  __shared__ float ynorm[8][512];
  const int tid = threadIdx.x;
  const int w = tid >> 6, lane = tid & 63;
  #pragma unroll
  for (int rr = 0; rr < 2; ++rr) {
    int l = 2 * w + rr;
    size_t t = (size_t)blockIdx.x * 8 + l;
    float v[8];
    float s = 0.f, sq = 0.f;
    #pragma unroll
    for (int j = 0; j < 8; ++j) {
      int k = lane + 64 * j;
      v[j] = y[t * D_ + k] + bfu2f(qbf[t * D_ + k]);
      s += v[j]; sq += v[j] * v[j];
    }
    #pragma unroll
    for (int o = 32; o > 0; o >>= 1) { s += __shfl_down(s, o); sq += __shfl_down(sq, o); }
    s = __shfl(s, 0); sq = __shfl(sq, 0);
    float mean = s * (1.0f / 512.0f);
    float var = sq * (1.0f / 512.0f) - mean * mean;
    float rstd = rsqrtf(var + 1e-5f);
    #pragma unroll
    for (int j = 0; j < 8; ++j) {
      int k = lane + 64 * j;
      ynorm[l][k] = (v[j] - mean) * rstd * g3[k] + be3[k];
    }
  }
  __syncthreads();
  float* ob = out + (size_t)blockIdx.x * 4096;
  #pragma unroll
  for (int kk = 0; kk < 2; ++kk) {
    int k = tid * 2 + kk;
    float4 lo = make_float4(ynorm[0][k], ynorm[1][k], ynorm[2][k], ynorm[3][k]);
    float4 hi = make_float4(ynorm[4][k], ynorm[5][k], ynorm[6][k], ynorm[7][k]);
    *reinterpret_cast<float4*>(ob + (size_t)k * 8)     = lo;
    *reinterpret_cast<float4*>(ob + (size_t)k * 8 + 4) = hi;
  }
}

// ================= slow-path fp32 kernels (fallback only) =================
#define TS 64
#define KT 16
__global__ __launch_bounds__(256) void k_build_x_s(const float* __restrict__ lags,
                                                   float* __restrict__ x, int b_base) {
  int idx = blockIdx.x * 256 + threadIdx.x;
  int k = idx & (D_ - 1);
  int r = idx >> 9;
  int b = b_base + r / SQ;
  int t = r - (r / SQ) * SQ;
  int si = t >> 3, l = t & 7;
  size_t src = (((size_t)(b * S_ + si) * D_ + k) << 3) + l;
  x[idx] = lags[src];
}

__global__ __launch_bounds__(256) void k_scores(const float* __restrict__ x,
                                                float* __restrict__ sc, int b_base) {
  const float* A = x;
  float* C = sc;
  __shared__ float As[TS][KT + 1];
  __shared__ float Bs[TS][KT + 1];
  int tx = threadIdx.x & 15, ty = threadIdx.x >> 4;
  int j0 = blockIdx.x * TS, i0 = blockIdx.y * TS;
  float acc[4][4] = {};
  int lk = threadIdx.x & 15, lr = threadIdx.x >> 4;
  for (int k0 = 0; k0 < D_; k0 += KT) {
    #pragma unroll
    for (int it = 0; it < 4; ++it) {
      As[lr + 16 * it][lk] = A[(size_t)(i0 + lr + 16 * it) * D_ + k0 + lk];
      Bs[lr + 16 * it][lk] = A[(size_t)(j0 + lr + 16 * it) * D_ + k0 + lk];
    }
    __syncthreads();
    #pragma unroll
    for (int kk = 0; kk < KT; ++kk) {
      float a[4], bb[4];
      #pragma unroll
      for (int r = 0; r < 4; ++r) a[r] = As[ty * 4 + r][kk];
      #pragma unroll
      for (int c = 0; c < 4; ++c) bb[c] = Bs[tx * 4 + c][kk];
      #pragma unroll
      for (int r = 0; r < 4; ++r)
        #pragma unroll
        for (int c = 0; c < 4; ++c) acc[r][c] = fmaf(a[r], bb[c], acc[r][c]);
    }
    __syncthreads();
  }
  #pragma unroll
  for (int r = 0; r < 4; ++r) {
    float4 v = make_float4(acc[r][0]*SCALE_QK, acc[r][1]*SCALE_QK,
                           acc[r][2]*SCALE_QK, acc[r][3]*SCALE_QK);
    *reinterpret_cast<float4*>(&C[(size_t)(i0 + ty*4 + r) * SQ + j0 + tx*4]) = v;
  }
}

__global__ __launch_bounds__(256) void k_softmax(float* __restrict__ sc) {
  float* row = sc + (size_t)blockIdx.x * SQ;
  int tid = threadIdx.x;
  __shared__ float red[8];
  float m = -1e30f;
  for (int j = tid; j < SQ; j += 256) m = fmaxf(m, row[j]);
  #pragma unroll
  for (int o = 32; o > 0; o >>= 1) m = fmaxf(m, __shfl_down(m, o));
  if ((tid & 63) == 0) red[tid >> 6] = m;
  __syncthreads();
  m = fmaxf(fmaxf(red[0], red[1]), fmaxf(red[2], red[3]));
  __syncthreads();
  float ssum = 0.f;
  for (int j = tid; j < SQ; j += 256) { float e = expf(row[j] - m); row[j] = e; ssum += e; }
  #pragma unroll
  for (int o = 32; o > 0; o >>= 1) ssum += __shfl_down(ssum, o);
  if ((tid & 63) == 0) red[4 + (tid >> 6)] = ssum;
  __syncthreads();
  float inv = 1.0f / (red[4] + red[5] + red[6] + red[7]);
  for (int j = tid; j < SQ; j += 256) row[j] *= inv;
}

__global__ __launch_bounds__(256) void k_attn(const float* __restrict__ x,
                                              const float* __restrict__ sc,
                                              float* __restrict__ attn) {
  const float* X = x;
  const float* P = sc;
  float* O = attn;
  __shared__ float Ps[TS][KT + 1];
  __shared__ float Xs[KT][TS];
  int tx = threadIdx.x & 15, ty = threadIdx.x >> 4;
  int j0 = blockIdx.x * TS, i0 = blockIdx.y * TS;
  float acc[4][4] = {};
  int lk = threadIdx.x & 15, lr = threadIdx.x >> 4;
  int lc = threadIdx.x & 63, lrow = threadIdx.x >> 6;
  for (int k0 = 0; k0 < SQ; k0 += KT) {
    #pragma unroll
    for (int it = 0; it < 4; ++it)
      Ps[lr + 16 * it][lk] = P[(size_t)(i0 + lr + 16 * it) * SQ + k0 + lk];
    #pragma unroll
    for (int it = 0; it < 4; ++it)
      Xs[lrow + 4 * it][lc] = X[(size_t)(k0 + lrow + 4 * it) * D_ + j0 + lc];
    __syncthreads();
    #pragma unroll
    for (int kk = 0; kk < KT; ++kk) {
      float a[4], bb[4];
      #pragma unroll
      for (int r = 0; r < 4; ++r) a[r] = Ps[ty * 4 + r][kk];
      #pragma unroll
      for (int c = 0; c < 4; ++c) bb[c] = Xs[kk][tx * 4 + c];
      #pragma unroll
      for (int r = 0; r < 4; ++r)
        #pragma unroll
        for (int c = 0; c < 4; ++c) acc[r][c] = fmaf(a[r], bb[c], acc[r][c]);
    }
    __syncthreads();
  }
  #pragma unroll
  for (int r = 0; r < 4; ++r) {
    float4 v = make_float4(acc[r][0], acc[r][1], acc[r][2], acc[r][3]);
    *reinterpret_cast<float4*>(&O[(size_t)(i0 + ty*4 + r) * D_ + j0 + tx*4]) = v;
  }
}

__global__ __launch_bounds__(256) void k_ln1(const float* __restrict__ x,
                                             const float* __restrict__ attn,
                                             const float* __restrict__ g,
                                             const float* __restrict__ be,
                                             float* __restrict__ qout) {
  size_t base = (size_t)blockIdx.x * D_;
  int tid = threadIdx.x;
  __shared__ float rl[8];
  float v0 = x[base + tid] + attn[base + tid];
  float v1 = x[base + tid + 256] + attn[base + tid + 256];
  float s = v0 + v1, sq = v0 * v0 + v1 * v1;
  #pragma unroll
  for (int o = 32; o > 0; o >>= 1) { s += __shfl_down(s, o); sq += __shfl_down(sq, o); }
  int lane = tid & 63, wid = tid >> 6;
  if (lane == 0) { rl[wid] = s; rl[4 + wid] = sq; }
  __syncthreads();
  s = rl[0] + rl[1] + rl[2] + rl[3];
  sq = rl[4] + rl[5] + rl[6] + rl[7];
  float mean = s * (1.0f / 512.0f);
  float var = sq * (1.0f / 512.0f) - mean * mean;
  float rstd = rsqrtf(var + 1e-5f);
  qout[base + tid]       = (v0 - mean) * rstd * g[tid] + be[tid];
  qout[base + tid + 256] = (v1 - mean) * rstd * g[tid + 256] + be[tid + 256];
}

__global__ __launch_bounds__(256, 2) void k_ffn(
    const float* __restrict__ q,
    const float* __restrict__ W1, const float* __restrict__ b1,
    const float* __restrict__ W2, const float* __restrict__ b2,
    const float* __restrict__ g3, const float* __restrict__ be3,
    float* __restrict__ out, int row_base)
{
  __shared__ float qs[8][D_];
  __shared__ float mid[8][H_];
  const int tid = threadIdx.x;
  const int row0 = blockIdx.x * 8;
  for (int idx = tid; idx < 8 * D_; idx += 256)
    qs[idx >> 9][idx & (D_ - 1)] = q[(size_t)row0 * D_ + idx];
  __syncthreads();
  float acc[8][8];
  {
    float4 bA = *reinterpret_cast<const float4*>(b1 + (tid << 3));
    float4 bB = *reinterpret_cast<const float4*>(b1 + (tid << 3) + 4);
    float bv[8] = {bA.x, bA.y, bA.z, bA.w, bB.x, bB.y, bB.z, bB.w};
    #pragma unroll
    for (int jj = 0; jj < 8; ++jj)
      #pragma unroll
      for (int r = 0; r < 8; ++r) acc[jj][r] = bv[jj];
  }
  for (int k4 = 0; k4 < D_ / 4; ++k4) {
    float4 qv[8];
    #pragma unroll
    for (int r = 0; r < 8; ++r)
      qv[r] = *reinterpret_cast<const float4*>(&qs[r][k4 << 2]);
    #pragma unroll
    for (int kk = 0; kk < 4; ++kk) {
      const int k = (k4 << 2) + kk;
      float4 wA = *reinterpret_cast<const float4*>(W1 + (size_t)k * H_ + (tid << 3));
      float4 wB = *reinterpret_cast<const float4*>(W1 + (size_t)k * H_ + (tid << 3) + 4);
      float wv[8] = {wA.x, wA.y, wA.z, wA.w, wB.x, wB.y, wB.z, wB.w};
      #pragma unroll
      for (int r = 0; r < 8; ++r) {
        float qk = (kk == 0) ? qv[r].x : (kk == 1) ? qv[r].y : (kk == 2) ? qv[r].z : qv[r].w;
        #pragma unroll
        for (int jj = 0; jj < 8; ++jj) acc[jj][r] = fmaf(qk, wv[jj], acc[jj][r]);
      }
    }
  }
  #pragma unroll
  for (int jj = 0; jj < 8; ++jj)
    #pragma unroll
    for (int r = 0; r < 8; ++r) {
      float v = acc[jj][r];
      mid[r][(tid << 3) + jj] = 0.5f * v * (1.0f + erff(v * 0.70710678118654752f));
    }
  __syncthreads();
  float acc2[8][2];
  {
    float b20 = b2[tid << 1], b21 = b2[(tid << 1) + 1];
    #pragma unroll
    for (int r = 0; r < 8; ++r) { acc2[r][0] = b20; acc2[r][1] = b21; }
  }
  for (int j4 = 0; j4 < H_ / 4; ++j4) {
    float4 mv[8];
    #pragma unroll
    for (int r = 0; r < 8; ++r)
      mv[r] = *reinterpret_cast<const float4*>(&mid[r][j4 << 2]);
    #pragma unroll
    for (int kk = 0; kk < 4; ++kk) {
      const int j = (j4 << 2) + kk;
      float2 wv = *reinterpret_cast<const float2*>(W2 + (size_t)j * D_ + (tid << 1));
      #pragma unroll
      for (int r = 0; r < 8; ++r) {
        float m = (kk == 0) ? mv[r].x : (kk == 1) ? mv[r].y : (kk == 2) ? mv[r].z : mv[r].w;
        acc2[r][0] = fmaf(m, wv.x, acc2[r][0]);
        acc2[r][1] = fmaf(m, wv.y, acc2[r][1]);
      }
    }
  }
  __syncthreads();
  float* ys = &mid[0][0];
  #pragma unroll
  for (int r = 0; r < 8; ++r) {
    ys[r * D_ + (tid << 1)]     = qs[r][(tid << 1)]     + acc2[r][0];
    ys[r * D_ + (tid << 1) + 1] = qs[r][(tid << 1) + 1] + acc2[r][1];
  }
  __syncthreads();
  float g3a = g3[tid],  g3b = g3[tid + 256];
  float be3a = be3[tid], be3b = be3[tid + 256];
  float* rl = &qs[0][0];
  for (int r = 0; r < 8; ++r) {
    float v0 = ys[r * D_ + tid], v1 = ys[r * D_ + tid + 256];
    float s = v0 + v1, sq = v0 * v0 + v1 * v1;
    #pragma unroll
    for (int o = 32; o > 0; o >>= 1) { s += __shfl_down(s, o); sq += __shfl_down(sq, o); }
    int lane = tid & 63, wid = tid >> 6;
    if (lane == 0) { rl[wid] = s; rl[4 + wid] = sq; }
    __syncthreads();
    s = rl[0] + rl[1] + rl[2] + rl[3];
    sq = rl[4] + rl[5] + rl[6] + rl[7];
    __syncthreads();
    float mean = s * (1.0f / 512.0f);
    float var = sq * (1.0f / 512.0f) - mean * mean;
    float rstd = rsqrtf(var + 1e-5f);
    int t = row_base + row0 + r;
    int b = t / SQ, tt = t - b * SQ;
    int si = tt >> 3, l = tt & 7;
    size_t ob = (((size_t)(b * S_ + si) * D_) << 3) + l;
    out[ob + ((size_t)tid << 3)]         = (v0 - mean) * rstd * g3a + be3a;
    out[ob + ((size_t)(tid + 256) << 3)] = (v1 - mean) * rstd * g3b + be3b;
  }
}

extern "C" void kernel_launch(void* const* d_in, const int* in_sizes, int n_in,
                              void* d_out, int out_size, void* d_ws, size_t ws_size,
                              hipStream_t stream) {
  const float* lags   = (const float*)d_in[0];
  const float* gamma1 = (const float*)d_in[1];
  const float* beta1  = (const float*)d_in[2];
  const float* W1     = (const float*)d_in[3];
  const float* b1     = (const float*)d_in[4];
  const float* W2     = (const float*)d_in[5];
  const float* b2     = (const float*)d_in[6];
  const float* g3     = (const float*)d_in[7];
  const float* be3    = (const float*)d_in[8];
  float* out = (float*)d_out;

  float* ws = (float*)d_ws;
  const size_t NX  = (size_t)B_ * SQ * D_;   // 6,291,456
  const size_t NXB = (size_t)SQ * D_;        //   786,432
  const size_t NS  = (size_t)SQ * SQ;        // 2,359,296

  const size_t need_full = (3 * NX + 8 * NS) * sizeof(float);  // ~151 MB (proven available)

  if (ws_size >= need_full) {
    // ---- fast path layout (~130 MB) ----
    float* x        = ws;                                   // NX f32
    float* attn     = x + NX;                               // NX f32 (later: y)
    ushort_t* q_bf  = (ushort_t*)(attn + NX);               // NX us
    ushort_t* w1t   = q_bf + NX;                            // H*D us
    ushort_t* w2t   = w1t + (size_t)H_ * D_;                // H*D us
    ushort_t* region = w2t + (size_t)H_ * D_;               // 8*NS + 2*NX us
    ushort_t* sc_bf = region;                               // scores / P, bf16, in-place
    ushort_t* x_bf  = region + 8 * NS;
    ushort_t* xT_bf = x_bf + NX;
    ushort_t* mid_bf = region;                              // aliases dead sc/x_bf/xT_bf

    k_build_x_f<<<dim3(B_ * S_), 256, 0, stream>>>(lags, x, x_bf);
    k_xt<<<dim3(SQ / 64, D_ / 64, B_), 256, 0, stream>>>(x_bf, xT_bf);
    k_wt<<<dim3(H_ / 64, D_ / 64), 256, 0, stream>>>(W1, w1t, D_, H_);
    k_wt<<<dim3(D_ / 64, H_ / 64), 256, 0, stream>>>(W2, w2t, H_, D_);
    // scores = scale * X X^T -> bf16
    k_gemm<2><<<dim3(SQ / 128, SQ / 128, B_), 256, 0, stream>>>(
        x_bf, x_bf, nullptr, sc_bf, SQ, D_, SQ, NXB, NXB, NS, SCALE_QK);
    k_softmax_bf<<<dim3(SQ, 1, B_), 256, 0, stream>>>(sc_bf);
    // attn = P @ X -> f32
    k_gemm<3><<<dim3(D_ / 128, SQ / 128, B_), 256, 0, stream>>>(
        sc_bf, xT_bf, nullptr, attn, SQ, SQ, D_, NS, NXB, NXB, 1.0f);
    k_ln1b<<<dim3(NROW), 256, 0, stream>>>(x, attn, gamma1, beta1, q_bf);
    // mid = gelu(q @ W1 + b1) -> bf16
    k_gemm<0><<<dim3(H_ / 128, NROW / 128, 1), 256, 0, stream>>>(
        q_bf, w1t, b1, mid_bf, NROW, D_, H_, 0, 0, 0, 1.0f);
    // y = mid @ W2 + b2 -> f32 (attn buffer)
    k_gemm<1><<<dim3(D_ / 128, NROW / 128, 1), 256, 0, stream>>>(
        mid_bf, w2t, b2, attn, NROW, H_, D_, 0, 0, 0, 1.0f);
    k_ln3_f<<<dim3(B_ * S_), 256, 0, stream>>>(attn, q_bf, g3, be3, out);
  } else {
    // ---- minimal-footprint fallback (fp32, per-batch) ----
    float* xb   = ws;
    float* sc   = xb + NXB;
    float* atb  = sc + NS;
    float* qb   = atb + NXB;
    for (int b = 0; b < B_; ++b) {
      k_build_x_s<<<dim3((unsigned)(NXB / 256)), 256, 0, stream>>>(lags, xb, b);
      k_scores<<<dim3(SQ / TS, SQ / TS, 1), 256, 0, stream>>>(xb, sc, b);
      k_softmax<<<dim3(SQ, 1, 1), 256, 0, stream>>>(sc);
      k_attn<<<dim3(D_ / TS, SQ / TS, 1), 256, 0, stream>>>(xb, sc, atb);
      k_ln1<<<dim3(SQ), 256, 0, stream>>>(xb, atb, gamma1, beta1, qb);
      k_ffn<<<dim3(SQ / 8), 256, 0, stream>>>(qb, W1, b1, W2, b2, g3, be3, out, b * SQ);
    }
  }
}